// Round 1
// baseline (2839.872 us; speedup 1.0000x reference)
//
#include <hip/hip_runtime.h>

#define NN   100000
#define EE   3200000
#define DD   256
#define DOUTC 64

// ---------------- BN column stats: sum and sumsq per column ----------------
__global__ void col_stats_kernel(const float* __restrict__ x, float* __restrict__ stats) {
    int t = threadIdx.x;            // column 0..255
    int r0 = blockIdx.x * 256;
    int r1 = min(r0 + 256, NN);
    float s = 0.f, s2 = 0.f;
    for (int r = r0; r < r1; ++r) {
        float v = x[(size_t)r * DD + t];
        s += v; s2 += v * v;
    }
    atomicAdd(&stats[t], s);
    atomicAdd(&stats[DD + t], s2);
}

// ---------------- fold BN affine into W_in / b_in ----------------
__global__ void fold_kernel(const float* __restrict__ stats,
                            const float* __restrict__ gamma,
                            const float* __restrict__ beta,
                            const float* __restrict__ w_in,
                            const float* __restrict__ b_in,
                            float* __restrict__ wfold,
                            float* __restrict__ bfold) {
    __shared__ float sa[DD], sb[DD];
    int t = threadIdx.x;
    float mean = stats[t] * (1.0f / NN);
    float var  = stats[DD + t] * (1.0f / NN) - mean * mean;
    float a = gamma[t] * rsqrtf(var + 1e-5f);
    sa[t] = a;
    sb[t] = beta[t] - mean * a;
    __syncthreads();
    float acc = 0.f;
    for (int j = 0; j < DD; ++j) {
        float w = w_in[j * DD + t];
        wfold[j * DD + t] = sa[j] * w;
        acc += sb[j] * w;
    }
    bfold[t] = b_in[t] + acc;
}

// ---------------- CSR build ----------------
__global__ void hist_kernel(const int* __restrict__ rows, int* __restrict__ cnt) {
    int e = blockIdx.x * blockDim.x + threadIdx.x;
    if (e < EE) atomicAdd(&cnt[rows[e]], 1);
}

__global__ void scan1_kernel(const int* __restrict__ in, int* __restrict__ out,
                             int* __restrict__ bsums, int n) {
    __shared__ int s[256];
    int t = threadIdx.x;
    int base = blockIdx.x * 1024;
    int v[4]; int local = 0;
    for (int i = 0; i < 4; ++i) {
        int idx = base + t * 4 + i;
        v[i] = (idx < n) ? in[idx] : 0;
        local += v[i];
    }
    s[t] = local;
    __syncthreads();
    for (int off = 1; off < 256; off <<= 1) {
        int xv = 0;
        if (t >= off) xv = s[t - off];
        __syncthreads();
        if (t >= off) s[t] += xv;
        __syncthreads();
    }
    int excl = s[t] - local;
    if (t == 255) bsums[blockIdx.x] = s[255];
    int run = excl;
    for (int i = 0; i < 4; ++i) {
        int idx = base + t * 4 + i;
        if (idx < n) out[idx] = run;
        run += v[i];
    }
}

__global__ void scan2_kernel(int* __restrict__ bsums, int nb) {
    __shared__ int s[256];
    int t = threadIdx.x;
    int v = (t < nb) ? bsums[t] : 0;
    s[t] = v;
    __syncthreads();
    for (int off = 1; off < 256; off <<= 1) {
        int xv = 0;
        if (t >= off) xv = s[t - off];
        __syncthreads();
        if (t >= off) s[t] += xv;
        __syncthreads();
    }
    if (t < nb) bsums[t] = s[t] - v;   // exclusive
}

__global__ void scan3_kernel(int* __restrict__ out, const int* __restrict__ bsums, int n) {
    int t = threadIdx.x;
    int base = blockIdx.x * 1024;
    int add = bsums[blockIdx.x];
    for (int i = 0; i < 4; ++i) {
        int idx = base + t * 4 + i;
        if (idx < n) out[idx] += add;
    }
    if (blockIdx.x == 0 && t == 0) out[n] = EE;
}

__global__ void scatter_kernel(const int* __restrict__ rows, const int* __restrict__ cols,
                               const float* __restrict__ vals, const int* __restrict__ rp,
                               int* __restrict__ cur, int2* __restrict__ edges) {
    int e = blockIdx.x * blockDim.x + threadIdx.x;
    if (e >= EE) return;
    int r = rows[e];
    int pos = rp[r] + atomicAdd(&cur[r], 1);
    edges[pos] = make_int2(cols[e], __float_as_int(vals[e]));
}

// ---------------- spmm: one wave per row, lane = 4 features ----------------
__global__ void spmm_kernel(const int* __restrict__ rp, const int2* __restrict__ edges,
                            const float* __restrict__ xin, float* __restrict__ xout) {
    int lane = threadIdx.x & 63;
    int r = blockIdx.x * 4 + (threadIdx.x >> 6);
    int e0 = rp[r], e1 = rp[r + 1];
    const float4* xi = (const float4*)xin;
    float4 a0 = {0,0,0,0}, a1 = {0,0,0,0}, a2 = {0,0,0,0}, a3 = {0,0,0,0};
    int e = e0;
    for (; e + 4 <= e1; e += 4) {
        int2 d0 = edges[e], d1 = edges[e+1], d2 = edges[e+2], d3 = edges[e+3];
        float4 x0 = xi[(size_t)d0.x * 64 + lane];
        float4 x1 = xi[(size_t)d1.x * 64 + lane];
        float4 x2 = xi[(size_t)d2.x * 64 + lane];
        float4 x3 = xi[(size_t)d3.x * 64 + lane];
        float v0 = __int_as_float(d0.y), v1 = __int_as_float(d1.y);
        float v2 = __int_as_float(d2.y), v3 = __int_as_float(d3.y);
        a0.x += v0*x0.x; a0.y += v0*x0.y; a0.z += v0*x0.z; a0.w += v0*x0.w;
        a1.x += v1*x1.x; a1.y += v1*x1.y; a1.z += v1*x1.z; a1.w += v1*x1.w;
        a2.x += v2*x2.x; a2.y += v2*x2.y; a2.z += v2*x2.z; a2.w += v2*x2.w;
        a3.x += v3*x3.x; a3.y += v3*x3.y; a3.z += v3*x3.z; a3.w += v3*x3.w;
    }
    for (; e < e1; ++e) {
        int2 d = edges[e];
        float4 xv = xi[(size_t)d.x * 64 + lane];
        float v = __int_as_float(d.y);
        a0.x += v*xv.x; a0.y += v*xv.y; a0.z += v*xv.z; a0.w += v*xv.w;
    }
    float4 o;
    o.x = (a0.x + a1.x) + (a2.x + a3.x);
    o.y = (a0.y + a1.y) + (a2.y + a3.y);
    o.z = (a0.z + a1.z) + (a2.z + a3.z);
    o.w = (a0.w + a1.w) + (a2.w + a3.w);
    ((float4*)xout)[(size_t)r * 64 + lane] = o;
}

// ---------------- fp32 GEMM: C = act(A[M x 256] @ W[256 x Nc] + bias) ----------------
// 128x64 block tile, 8x4 per thread, K-chunk 32.
__global__ __launch_bounds__(256) void gemm_kernel(
    const float* __restrict__ A, const float* __restrict__ W,
    const float* __restrict__ bias, float* __restrict__ C,
    int M, int Nc, int do_tanh) {
    __shared__ float As[32][132];
    __shared__ float Ws[32][64];
    int tid = threadIdx.x;
    int tx = tid & 15, ty = tid >> 4;
    int m0 = blockIdx.x * 128, n0 = blockIdx.y * 64;
    float acc[8][4];
#pragma unroll
    for (int i = 0; i < 8; ++i)
#pragma unroll
        for (int j = 0; j < 4; ++j) acc[i][j] = 0.f;

    for (int k0 = 0; k0 < 256; k0 += 32) {
#pragma unroll
        for (int p = 0; p < 4; ++p) {
            int idx = tid + p * 256;         // [0,1024)
            int m = idx >> 3, kv = idx & 7;
            int gm = m0 + m;
            float4 av = make_float4(0.f, 0.f, 0.f, 0.f);
            if (gm < M) av = *(const float4*)&A[(size_t)gm * 256 + k0 + kv * 4];
            As[kv*4+0][m] = av.x;
            As[kv*4+1][m] = av.y;
            As[kv*4+2][m] = av.z;
            As[kv*4+3][m] = av.w;
        }
#pragma unroll
        for (int p = 0; p < 2; ++p) {
            int idx = tid + p * 256;         // [0,512)
            int k = idx >> 4, nv = idx & 15;
            float4 wv = *(const float4*)&W[(size_t)(k0 + k) * Nc + n0 + nv * 4];
            *(float4*)&Ws[k][nv*4] = wv;
        }
        __syncthreads();
#pragma unroll
        for (int kk = 0; kk < 32; ++kk) {
            float4 aa0 = *(const float4*)&As[kk][ty*8];
            float4 aa1 = *(const float4*)&As[kk][ty*8+4];
            float4 ww  = *(const float4*)&Ws[kk][tx*4];
            float am[8] = {aa0.x,aa0.y,aa0.z,aa0.w,aa1.x,aa1.y,aa1.z,aa1.w};
            float wn[4] = {ww.x,ww.y,ww.z,ww.w};
#pragma unroll
            for (int i = 0; i < 8; ++i)
#pragma unroll
                for (int j = 0; j < 4; ++j)
                    acc[i][j] += am[i] * wn[j];
        }
        __syncthreads();
    }

    float4 bv = *(const float4*)&bias[n0 + tx*4];
    float bb[4] = {bv.x, bv.y, bv.z, bv.w};
#pragma unroll
    for (int i = 0; i < 8; ++i) {
        int gm = m0 + ty*8 + i;
        if (gm >= M) break;
        float4 o;
        float vx = acc[i][0] + bb[0];
        float vy = acc[i][1] + bb[1];
        float vz = acc[i][2] + bb[2];
        float vw = acc[i][3] + bb[3];
        if (do_tanh) { vx = tanhf(vx); vy = tanhf(vy); vz = tanhf(vz); vw = tanhf(vw); }
        o.x = vx; o.y = vy; o.z = vz; o.w = vw;
        *(float4*)&C[(size_t)gm * Nc + n0 + tx*4] = o;
    }
}

extern "C" void kernel_launch(void* const* d_in, const int* in_sizes, int n_in,
                              void* d_out, int out_size, void* d_ws, size_t ws_size,
                              hipStream_t stream) {
    const float* x      = (const float*)d_in[0];
    const int*   erows  = (const int*)d_in[1];
    const int*   ecols  = (const int*)d_in[2];
    const float* evals  = (const float*)d_in[3];
    const float* gamma  = (const float*)d_in[4];
    const float* beta   = (const float*)d_in[5];
    const float* w_in   = (const float*)d_in[6];
    const float* b_in   = (const float*)d_in[7];
    const float* w_conv = (const float*)d_in[8];
    const float* b_conv = (const float*)d_in[9];
    const float* w_out  = (const float*)d_in[10];
    const float* b_out  = (const float*)d_in[11];
    float* out = (float*)d_out;

    char* ws = (char*)d_ws;
    size_t off = 0;
    auto alloc = [&](size_t bytes) -> void* {
        void* p = ws + off;
        off = (off + bytes + 255) & ~(size_t)255;
        return p;
    };
    float* h1    = (float*)alloc((size_t)NN * DD * 4);
    float* h2    = (float*)alloc((size_t)NN * DD * 4);
    int2*  edges = (int2*) alloc((size_t)EE * 8);
    int*   rp    = (int*)  alloc((size_t)(NN + 1) * 4);
    int*   cnt   = (int*)  alloc((size_t)NN * 4);
    int*   cur   = (int*)  alloc((size_t)NN * 4);
    float* stats = (float*)alloc(2 * DD * 4);
    int*   bsums = (int*)  alloc(128 * 4);
    float* wfold = (float*)alloc((size_t)DD * DD * 4);
    float* bfold = (float*)alloc(DD * 4);

    hipMemsetAsync(cnt,   0, (size_t)NN * 4, stream);
    hipMemsetAsync(cur,   0, (size_t)NN * 4, stream);
    hipMemsetAsync(stats, 0, 2 * DD * 4, stream);

    // CSR build
    hist_kernel<<<(EE + 255) / 256, 256, 0, stream>>>(erows, cnt);
    int nb = (NN + 1023) / 1024;   // 98
    scan1_kernel<<<nb, 256, 0, stream>>>(cnt, rp, bsums, NN);
    scan2_kernel<<<1, 256, 0, stream>>>(bsums, nb);
    scan3_kernel<<<nb, 256, 0, stream>>>(rp, bsums, NN);
    scatter_kernel<<<(EE + 255) / 256, 256, 0, stream>>>(erows, ecols, evals, rp, cur, edges);

    // BN stats + fold into GEMM1 weights
    col_stats_kernel<<<(NN + 255) / 256, 256, 0, stream>>>(x, stats);
    fold_kernel<<<1, 256, 0, stream>>>(stats, gamma, beta, w_in, b_in, wfold, bfold);

    // GEMM1 (BN folded) + tanh
    gemm_kernel<<<dim3((NN + 127) / 128, DD / 64), 256, 0, stream>>>(x, wfold, bfold, h1, NN, DD, 1);

    // 4 spmm hops
    spmm_kernel<<<NN / 4, 256, 0, stream>>>(rp, edges, h1, h2);
    spmm_kernel<<<NN / 4, 256, 0, stream>>>(rp, edges, h2, h1);
    spmm_kernel<<<NN / 4, 256, 0, stream>>>(rp, edges, h1, h2);
    spmm_kernel<<<NN / 4, 256, 0, stream>>>(rp, edges, h2, h1);

    // GEMM2 + tanh
    gemm_kernel<<<dim3((NN + 127) / 128, DD / 64), 256, 0, stream>>>(h1, w_conv, b_conv, h2, NN, DD, 1);
    // GEMM3 (logits)
    gemm_kernel<<<dim3((NN + 127) / 128, DOUTC / 64), 256, 0, stream>>>(h2, w_out, b_out, out, NN, DOUTC, 0);
}

// Round 2
// 1874.758 us; speedup vs baseline: 1.5148x; 1.5148x over previous
//
#include <hip/hip_runtime.h>
#include <hip/hip_fp16.h>

#define NN   100000
#define EE   3200000
#define DD   256
#define DOUTC 64

// ---------------- BN column stats: sum and sumsq per column ----------------
__global__ void col_stats_kernel(const float* __restrict__ x, float* __restrict__ stats) {
    int t = threadIdx.x;            // column 0..255
    int r0 = blockIdx.x * 256;
    int r1 = min(r0 + 256, NN);
    float s = 0.f, s2 = 0.f;
    for (int r = r0; r < r1; ++r) {
        float v = x[(size_t)r * DD + t];
        s += v; s2 += v * v;
    }
    atomicAdd(&stats[t], s);
    atomicAdd(&stats[DD + t], s2);
}

// ---------------- fold BN affine into W_in / b_in ----------------
__global__ void fold_kernel(const float* __restrict__ stats,
                            const float* __restrict__ gamma,
                            const float* __restrict__ beta,
                            const float* __restrict__ w_in,
                            const float* __restrict__ b_in,
                            float* __restrict__ wfold,
                            float* __restrict__ bfold) {
    __shared__ float sa[DD], sb[DD];
    int t = threadIdx.x;
    float mean = stats[t] * (1.0f / NN);
    float var  = stats[DD + t] * (1.0f / NN) - mean * mean;
    float a = gamma[t] * rsqrtf(var + 1e-5f);
    sa[t] = a;
    sb[t] = beta[t] - mean * a;
    __syncthreads();
    float acc = 0.f;
    for (int j = 0; j < DD; ++j) {
        float w = w_in[j * DD + t];
        wfold[j * DD + t] = sa[j] * w;
        acc += sb[j] * w;
    }
    bfold[t] = b_in[t] + acc;
}

// ---------------- CSR build ----------------
__global__ void hist_kernel(const int* __restrict__ rows, int* __restrict__ cnt) {
    int e = blockIdx.x * blockDim.x + threadIdx.x;
    if (e < EE) atomicAdd(&cnt[rows[e]], 1);
}

__global__ void scan1_kernel(const int* __restrict__ in, int* __restrict__ out,
                             int* __restrict__ bsums, int n) {
    __shared__ int s[256];
    int t = threadIdx.x;
    int base = blockIdx.x * 1024;
    int v[4]; int local = 0;
    for (int i = 0; i < 4; ++i) {
        int idx = base + t * 4 + i;
        v[i] = (idx < n) ? in[idx] : 0;
        local += v[i];
    }
    s[t] = local;
    __syncthreads();
    for (int off = 1; off < 256; off <<= 1) {
        int xv = 0;
        if (t >= off) xv = s[t - off];
        __syncthreads();
        if (t >= off) s[t] += xv;
        __syncthreads();
    }
    int excl = s[t] - local;
    if (t == 255) bsums[blockIdx.x] = s[255];
    int run = excl;
    for (int i = 0; i < 4; ++i) {
        int idx = base + t * 4 + i;
        if (idx < n) out[idx] = run;
        run += v[i];
    }
}

__global__ void scan2_kernel(int* __restrict__ bsums, int nb) {
    __shared__ int s[256];
    int t = threadIdx.x;
    int v = (t < nb) ? bsums[t] : 0;
    s[t] = v;
    __syncthreads();
    for (int off = 1; off < 256; off <<= 1) {
        int xv = 0;
        if (t >= off) xv = s[t - off];
        __syncthreads();
        if (t >= off) s[t] += xv;
        __syncthreads();
    }
    if (t < nb) bsums[t] = s[t] - v;   // exclusive
}

__global__ void scan3_kernel(int* __restrict__ out, const int* __restrict__ bsums, int n) {
    int t = threadIdx.x;
    int base = blockIdx.x * 1024;
    int add = bsums[blockIdx.x];
    for (int i = 0; i < 4; ++i) {
        int idx = base + t * 4 + i;
        if (idx < n) out[idx] += add;
    }
    if (blockIdx.x == 0 && t == 0) out[n] = EE;
}

__global__ void scatter_kernel(const int* __restrict__ rows, const int* __restrict__ cols,
                               const float* __restrict__ vals, const int* __restrict__ rp,
                               int* __restrict__ cur, int2* __restrict__ edges) {
    int e = blockIdx.x * blockDim.x + threadIdx.x;
    if (e >= EE) return;
    int r = rows[e];
    int pos = rp[r] + atomicAdd(&cur[r], 1);
    edges[pos] = make_int2(cols[e], __float_as_int(vals[e]));
}

// ---------------- spmm (fp16 storage, fp32 accum) ----------------
// One wave per row. Half-wave pairs: lanes 0-31 handle even edge of a pair,
// lanes 32-63 the odd edge. Each lane loads 16B = 8 fp16 features.
// Unroll 4 pairs -> 8 edges (8x16B gathers) in flight per wave.
__global__ __launch_bounds__(256) void spmm_kernel(
        const int* __restrict__ rp, const int2* __restrict__ edges,
        const __half* __restrict__ xin, __half* __restrict__ xout) {
    int tid = threadIdx.x;
    int lane = tid & 63;
    int half_id = lane >> 5;     // 0 or 1
    int sl = lane & 31;          // feature group: features [sl*8, sl*8+8)
    int r = __builtin_amdgcn_readfirstlane(blockIdx.x * 4 + (tid >> 6));
    int e0 = rp[r], e1 = rp[r + 1];
    const float4* xi = (const float4*)xin;   // 32 x float4 per row (512B)

    float acc[8] = {0.f,0.f,0.f,0.f,0.f,0.f,0.f,0.f};

    int base = e0;
    for (; base + 8 <= e1; base += 8) {
        int2 d[4];
#pragma unroll
        for (int i = 0; i < 4; ++i) d[i] = edges[base + 2*i + half_id];
        float4 xv[4];
#pragma unroll
        for (int i = 0; i < 4; ++i) xv[i] = xi[(size_t)d[i].x * 32 + sl];
#pragma unroll
        for (int i = 0; i < 4; ++i) {
            float v = __int_as_float(d[i].y);
            const __half2* hp = (const __half2*)&xv[i];
            float2 f0 = __half22float2(hp[0]);
            float2 f1 = __half22float2(hp[1]);
            float2 f2 = __half22float2(hp[2]);
            float2 f3 = __half22float2(hp[3]);
            acc[0] += v*f0.x; acc[1] += v*f0.y;
            acc[2] += v*f1.x; acc[3] += v*f1.y;
            acc[4] += v*f2.x; acc[5] += v*f2.y;
            acc[6] += v*f3.x; acc[7] += v*f3.y;
        }
    }
    if (base < e1) {             // tail: 1..7 edges, masked batch
#pragma unroll
        for (int i = 0; i < 4; ++i) {
            int idx = base + 2*i + half_id;
            bool valid = idx < e1;
            int idxc = valid ? idx : e0;
            int2 d = edges[idxc];
            float v = valid ? __int_as_float(d.y) : 0.f;
            float4 xv = xi[(size_t)d.x * 32 + sl];
            const __half2* hp = (const __half2*)&xv;
            float2 f0 = __half22float2(hp[0]);
            float2 f1 = __half22float2(hp[1]);
            float2 f2 = __half22float2(hp[2]);
            float2 f3 = __half22float2(hp[3]);
            acc[0] += v*f0.x; acc[1] += v*f0.y;
            acc[2] += v*f1.x; acc[3] += v*f1.y;
            acc[4] += v*f2.x; acc[5] += v*f2.y;
            acc[6] += v*f3.x; acc[7] += v*f3.y;
        }
    }
    // combine the two half-waves
#pragma unroll
    for (int j = 0; j < 8; ++j) acc[j] += __shfl_xor(acc[j], 32, 64);
    if (half_id == 0) {
        union { __half h[8]; float4 f; } u;
#pragma unroll
        for (int j = 0; j < 8; ++j) u.h[j] = __float2half_rn(acc[j]);
        ((float4*)xout)[(size_t)r * 32 + sl] = u.f;
    }
}

// ---------------- fp32-compute GEMM, templated in/out dtype ----------------
__device__ inline float4 load4(const float* p) { return *(const float4*)p; }
__device__ inline float4 load4(const __half* p) {
    __half2 h01 = *(const __half2*)p;
    __half2 h23 = *(const __half2*)(p + 2);
    float2 f01 = __half22float2(h01), f23 = __half22float2(h23);
    return make_float4(f01.x, f01.y, f23.x, f23.y);
}
__device__ inline void store4(float* p, float4 v) { *(float4*)p = v; }
__device__ inline void store4(__half* p, float4 v) {
    union { __half2 h2[2]; float2 f; } u;
    u.h2[0] = __floats2half2_rn(v.x, v.y);
    u.h2[1] = __floats2half2_rn(v.z, v.w);
    *(float2*)p = u.f;
}

// C = act(A[M x 256] @ W[256 x Nc] + bias); 128x64 tile, 8x4 per thread.
template <typename Tin, typename Tout>
__global__ __launch_bounds__(256) void gemm_kernel(
    const Tin* __restrict__ A, const float* __restrict__ W,
    const float* __restrict__ bias, Tout* __restrict__ C,
    int M, int Nc, int do_tanh) {
    __shared__ float As[32][132];
    __shared__ float Ws[32][64];
    int tid = threadIdx.x;
    int tx = tid & 15, ty = tid >> 4;
    int m0 = blockIdx.x * 128, n0 = blockIdx.y * 64;
    float acc[8][4];
#pragma unroll
    for (int i = 0; i < 8; ++i)
#pragma unroll
        for (int j = 0; j < 4; ++j) acc[i][j] = 0.f;

    for (int k0 = 0; k0 < 256; k0 += 32) {
#pragma unroll
        for (int p = 0; p < 4; ++p) {
            int idx = tid + p * 256;         // [0,1024)
            int m = idx >> 3, kv = idx & 7;
            int gm = m0 + m;
            float4 av = make_float4(0.f, 0.f, 0.f, 0.f);
            if (gm < M) av = load4(&A[(size_t)gm * 256 + k0 + kv * 4]);
            As[kv*4+0][m] = av.x;
            As[kv*4+1][m] = av.y;
            As[kv*4+2][m] = av.z;
            As[kv*4+3][m] = av.w;
        }
#pragma unroll
        for (int p = 0; p < 2; ++p) {
            int idx = tid + p * 256;         // [0,512)
            int k = idx >> 4, nv = idx & 15;
            float4 wv = *(const float4*)&W[(size_t)(k0 + k) * Nc + n0 + nv * 4];
            *(float4*)&Ws[k][nv*4] = wv;
        }
        __syncthreads();
#pragma unroll
        for (int kk = 0; kk < 32; ++kk) {
            float4 aa0 = *(const float4*)&As[kk][ty*8];
            float4 aa1 = *(const float4*)&As[kk][ty*8+4];
            float4 ww  = *(const float4*)&Ws[kk][tx*4];
            float am[8] = {aa0.x,aa0.y,aa0.z,aa0.w,aa1.x,aa1.y,aa1.z,aa1.w};
            float wn[4] = {ww.x,ww.y,ww.z,ww.w};
#pragma unroll
            for (int i = 0; i < 8; ++i)
#pragma unroll
                for (int j = 0; j < 4; ++j)
                    acc[i][j] += am[i] * wn[j];
        }
        __syncthreads();
    }

    float4 bv = *(const float4*)&bias[n0 + tx*4];
    float bb[4] = {bv.x, bv.y, bv.z, bv.w};
#pragma unroll
    for (int i = 0; i < 8; ++i) {
        int gm = m0 + ty*8 + i;
        if (gm >= M) break;
        float4 o;
        float vx = acc[i][0] + bb[0];
        float vy = acc[i][1] + bb[1];
        float vz = acc[i][2] + bb[2];
        float vw = acc[i][3] + bb[3];
        if (do_tanh) { vx = tanhf(vx); vy = tanhf(vy); vz = tanhf(vz); vw = tanhf(vw); }
        o.x = vx; o.y = vy; o.z = vz; o.w = vw;
        store4(&C[(size_t)gm * Nc + n0 + tx*4], o);
    }
}

extern "C" void kernel_launch(void* const* d_in, const int* in_sizes, int n_in,
                              void* d_out, int out_size, void* d_ws, size_t ws_size,
                              hipStream_t stream) {
    const float* x      = (const float*)d_in[0];
    const int*   erows  = (const int*)d_in[1];
    const int*   ecols  = (const int*)d_in[2];
    const float* evals  = (const float*)d_in[3];
    const float* gamma  = (const float*)d_in[4];
    const float* beta   = (const float*)d_in[5];
    const float* w_in   = (const float*)d_in[6];
    const float* b_in   = (const float*)d_in[7];
    const float* w_conv = (const float*)d_in[8];
    const float* b_conv = (const float*)d_in[9];
    const float* w_out  = (const float*)d_in[10];
    const float* b_out  = (const float*)d_in[11];
    float* out = (float*)d_out;

    char* ws = (char*)d_ws;
    size_t off = 0;
    auto alloc = [&](size_t bytes) -> void* {
        void* p = ws + off;
        off = (off + bytes + 255) & ~(size_t)255;
        return p;
    };
    __half* h1   = (__half*)alloc((size_t)NN * DD * 2);
    __half* h2   = (__half*)alloc((size_t)NN * DD * 2);
    int2*  edges = (int2*) alloc((size_t)EE * 8);
    int*   rp    = (int*)  alloc((size_t)(NN + 1) * 4);
    int*   cnt   = (int*)  alloc((size_t)NN * 4);
    int*   cur   = (int*)  alloc((size_t)NN * 4);
    float* stats = (float*)alloc(2 * DD * 4);
    int*   bsums = (int*)  alloc(128 * 4);
    float* wfold = (float*)alloc((size_t)DD * DD * 4);
    float* bfold = (float*)alloc(DD * 4);

    hipMemsetAsync(cnt,   0, (size_t)NN * 4, stream);
    hipMemsetAsync(cur,   0, (size_t)NN * 4, stream);
    hipMemsetAsync(stats, 0, 2 * DD * 4, stream);

    // CSR build
    hist_kernel<<<(EE + 255) / 256, 256, 0, stream>>>(erows, cnt);
    int nb = (NN + 1023) / 1024;   // 98
    scan1_kernel<<<nb, 256, 0, stream>>>(cnt, rp, bsums, NN);
    scan2_kernel<<<1, 256, 0, stream>>>(bsums, nb);
    scan3_kernel<<<nb, 256, 0, stream>>>(rp, bsums, NN);
    scatter_kernel<<<(EE + 255) / 256, 256, 0, stream>>>(erows, ecols, evals, rp, cur, edges);

    // BN stats + fold into GEMM1 weights
    col_stats_kernel<<<(NN + 255) / 256, 256, 0, stream>>>(x, stats);
    fold_kernel<<<1, 256, 0, stream>>>(stats, gamma, beta, w_in, b_in, wfold, bfold);

    // GEMM1 (BN folded) + tanh -> fp16
    gemm_kernel<<<dim3((NN + 127) / 128, DD / 64), 256, 0, stream>>>(x, wfold, bfold, h1, NN, DD, 1);

    // 4 spmm hops (fp16 storage, fp32 accum)
    spmm_kernel<<<NN / 4, 256, 0, stream>>>(rp, edges, h1, h2);
    spmm_kernel<<<NN / 4, 256, 0, stream>>>(rp, edges, h2, h1);
    spmm_kernel<<<NN / 4, 256, 0, stream>>>(rp, edges, h1, h2);
    spmm_kernel<<<NN / 4, 256, 0, stream>>>(rp, edges, h2, h1);

    // GEMM2 + tanh (fp16 in, fp16 out)
    gemm_kernel<<<dim3((NN + 127) / 128, DD / 64), 256, 0, stream>>>(h1, w_conv, b_conv, h2, NN, DD, 1);
    // GEMM3 (fp16 in, fp32 logits out)
    gemm_kernel<<<dim3((NN + 127) / 128, DOUTC / 64), 256, 0, stream>>>(h2, w_out, b_out, out, NN, DOUTC, 0);
}

// Round 3
// 1671.092 us; speedup vs baseline: 1.6994x; 1.1219x over previous
//
#include <hip/hip_runtime.h>
#include <hip/hip_fp16.h>

#define NN   100000
#define NNP  100096          // 782 * 128, padded row count for hop/GEMM buffers
#define EE   3200000
#define DD   256
#define DOUTC 64
#define LSTR 40              // LDS row stride in halves (80 B, 16B-aligned, 2-way bank alias = free)

typedef _Float16 half8 __attribute__((ext_vector_type(8)));
typedef _Float16 half4 __attribute__((ext_vector_type(4)));
typedef float    f32x4 __attribute__((ext_vector_type(4)));

__device__ inline f32x4 mfma16(half8 a, half8 b, f32x4 c) {
    return __builtin_amdgcn_mfma_f32_16x16x32_f16(a, b, c, 0, 0, 0);
}

// ---------------- BN column stats: sum and sumsq per column ----------------
__global__ void col_stats_kernel(const float* __restrict__ x, float* __restrict__ stats) {
    int t = threadIdx.x;            // column 0..255
    int r0 = blockIdx.x * 256;
    int r1 = min(r0 + 256, NN);
    float s = 0.f, s2 = 0.f;
    for (int r = r0; r < r1; ++r) {
        float v = x[(size_t)r * DD + t];
        s += v; s2 += v * v;
    }
    atomicAdd(&stats[t], s);
    atomicAdd(&stats[DD + t], s2);
}

// ---------------- fold BN bias: bfold = b_in + sum_j sb[j] * w_in[j][:] ----------------
__global__ void fold_bias_kernel(const float* __restrict__ stats,
                                 const float* __restrict__ gamma,
                                 const float* __restrict__ beta,
                                 const float* __restrict__ w_in,
                                 const float* __restrict__ b_in,
                                 float* __restrict__ bfold) {
    __shared__ float sb[DD];
    int t = threadIdx.x;
    float mean = stats[t] * (1.0f / NN);
    float var  = stats[DD + t] * (1.0f / NN) - mean * mean;
    float a = gamma[t] * rsqrtf(var + 1e-5f);
    sb[t] = beta[t] - mean * a;
    __syncthreads();
    float acc = 0.f;
    for (int j = 0; j < DD; ++j) acc += sb[j] * w_in[j * DD + t];
    bfold[t] = b_in[t] + acc;
}

// ---------------- split W (BN-scaled) into transposed hi/lo fp16: WT[n][k] ----------------
__global__ void split_w1_kernel(const float* __restrict__ stats,
                                const float* __restrict__ gamma,
                                const float* __restrict__ w_in,
                                _Float16* __restrict__ wth, _Float16* __restrict__ wtl) {
    int k = blockIdx.x, n = threadIdx.x;
    float mean = stats[k] * (1.0f / NN);
    float var  = stats[DD + k] * (1.0f / NN) - mean * mean;
    float a = gamma[k] * rsqrtf(var + 1e-5f);
    float v = a * w_in[(size_t)k * DD + n];
    _Float16 hi = (_Float16)v;
    _Float16 lo = (_Float16)(v - (float)hi);
    wth[(size_t)n * DD + k] = hi;
    wtl[(size_t)n * DD + k] = lo;
}

__global__ void split_w_kernel(const float* __restrict__ w, int ncols,
                               _Float16* __restrict__ wth, _Float16* __restrict__ wtl) {
    int k = blockIdx.x, n = threadIdx.x;   // w is [256][ncols]
    float v = w[(size_t)k * ncols + n];
    _Float16 hi = (_Float16)v;
    _Float16 lo = (_Float16)(v - (float)hi);
    wth[(size_t)n * DD + k] = hi;
    wtl[(size_t)n * DD + k] = lo;
}

// ---------------- CSR build ----------------
__global__ void hist_kernel(const int* __restrict__ rows, int* __restrict__ cnt) {
    int e = blockIdx.x * blockDim.x + threadIdx.x;
    if (e < EE) atomicAdd(&cnt[rows[e]], 1);
}

__global__ void scan1_kernel(const int* __restrict__ in, int* __restrict__ out,
                             int* __restrict__ bsums, int n) {
    __shared__ int s[256];
    int t = threadIdx.x;
    int base = blockIdx.x * 1024;
    int v[4]; int local = 0;
    for (int i = 0; i < 4; ++i) {
        int idx = base + t * 4 + i;
        v[i] = (idx < n) ? in[idx] : 0;
        local += v[i];
    }
    s[t] = local;
    __syncthreads();
    for (int off = 1; off < 256; off <<= 1) {
        int xv = 0;
        if (t >= off) xv = s[t - off];
        __syncthreads();
        if (t >= off) s[t] += xv;
        __syncthreads();
    }
    int excl = s[t] - local;
    if (t == 255) bsums[blockIdx.x] = s[255];
    int run = excl;
    for (int i = 0; i < 4; ++i) {
        int idx = base + t * 4 + i;
        if (idx < n) out[idx] = run;
        run += v[i];
    }
}

__global__ void scan2_kernel(int* __restrict__ bsums, int nb) {
    __shared__ int s[256];
    int t = threadIdx.x;
    int v = (t < nb) ? bsums[t] : 0;
    s[t] = v;
    __syncthreads();
    for (int off = 1; off < 256; off <<= 1) {
        int xv = 0;
        if (t >= off) xv = s[t - off];
        __syncthreads();
        if (t >= off) s[t] += xv;
        __syncthreads();
    }
    if (t < nb) bsums[t] = s[t] - v;   // exclusive
}

__global__ void scan3_kernel(int* __restrict__ out, const int* __restrict__ bsums, int n) {
    int t = threadIdx.x;
    int base = blockIdx.x * 1024;
    int add = bsums[blockIdx.x];
    for (int i = 0; i < 4; ++i) {
        int idx = base + t * 4 + i;
        if (idx < n) out[idx] += add;
    }
    if (blockIdx.x == 0 && t == 0) out[n] = EE;
}

__global__ void scatter_kernel(const int* __restrict__ rows, const int* __restrict__ cols,
                               const float* __restrict__ vals, const int* __restrict__ rp,
                               int* __restrict__ cur, int2* __restrict__ edges) {
    int e = blockIdx.x * blockDim.x + threadIdx.x;
    if (e >= EE) return;
    int r = rows[e];
    int pos = rp[r] + atomicAdd(&cur[r], 1);
    edges[pos] = make_int2(cols[e], __float_as_int(vals[e]));
}

// ---------------- spmm (fp16 storage, fp32 accum) ----------------
__global__ __launch_bounds__(256) void spmm_kernel(
        const int* __restrict__ rp, const int2* __restrict__ edges,
        const __half* __restrict__ xin, __half* __restrict__ xout) {
    int tid = threadIdx.x;
    int lane = tid & 63;
    int half_id = lane >> 5;     // 0 or 1
    int sl = lane & 31;          // feature group: features [sl*8, sl*8+8)
    int r = __builtin_amdgcn_readfirstlane(blockIdx.x * 4 + (tid >> 6));
    int e0 = rp[r], e1 = rp[r + 1];
    const float4* xi = (const float4*)xin;   // 32 x float4 per row (512B)

    float acc[8] = {0.f,0.f,0.f,0.f,0.f,0.f,0.f,0.f};

    int base = e0;
    for (; base + 8 <= e1; base += 8) {
        int2 d[4];
#pragma unroll
        for (int i = 0; i < 4; ++i) d[i] = edges[base + 2*i + half_id];
        float4 xv[4];
#pragma unroll
        for (int i = 0; i < 4; ++i) xv[i] = xi[(size_t)d[i].x * 32 + sl];
#pragma unroll
        for (int i = 0; i < 4; ++i) {
            float v = __int_as_float(d[i].y);
            const __half2* hp = (const __half2*)&xv[i];
            float2 f0 = __half22float2(hp[0]);
            float2 f1 = __half22float2(hp[1]);
            float2 f2 = __half22float2(hp[2]);
            float2 f3 = __half22float2(hp[3]);
            acc[0] += v*f0.x; acc[1] += v*f0.y;
            acc[2] += v*f1.x; acc[3] += v*f1.y;
            acc[4] += v*f2.x; acc[5] += v*f2.y;
            acc[6] += v*f3.x; acc[7] += v*f3.y;
        }
    }
    if (base < e1) {             // tail: 1..7 edges, masked batch
#pragma unroll
        for (int i = 0; i < 4; ++i) {
            int idx = base + 2*i + half_id;
            bool valid = idx < e1;
            int idxc = valid ? idx : e0;
            int2 d = edges[idxc];
            float v = valid ? __int_as_float(d.y) : 0.f;
            float4 xv = xi[(size_t)d.x * 32 + sl];
            const __half2* hp = (const __half2*)&xv;
            float2 f0 = __half22float2(hp[0]);
            float2 f1 = __half22float2(hp[1]);
            float2 f2 = __half22float2(hp[2]);
            float2 f3 = __half22float2(hp[3]);
            acc[0] += v*f0.x; acc[1] += v*f0.y;
            acc[2] += v*f1.x; acc[3] += v*f1.y;
            acc[4] += v*f2.x; acc[5] += v*f2.y;
            acc[6] += v*f3.x; acc[7] += v*f3.y;
        }
    }
#pragma unroll
    for (int j = 0; j < 8; ++j) acc[j] += __shfl_xor(acc[j], 32, 64);
    if (half_id == 0) {
        union { __half h[8]; float4 f; } u;
#pragma unroll
        for (int j = 0; j < 8; ++j) u.h[j] = __float2half_rn(acc[j]);
        ((float4*)xout)[(size_t)r * 32 + sl] = u.f;
    }
}

// ---------------- MFMA GEMM with split-fp16 precision ----------------
// C[M x NC] = act(A[M x 256] @ W + bias), W pre-split+transposed: WT[n][k] fp16 hi/lo.
// BM=128, BK=32, per-wave 64x64 (BN=128) or 32x64 (BN=64).
// SPLIT_A: A is fp32, split into hi/lo in LDS; 3 MFMA products. Else A fp16; 2 products.
template<bool SPLIT_A, bool TANH, typename Tout, int BN>
__global__ __launch_bounds__(256) void gemm_mfma(
    const void* __restrict__ Av, const _Float16* __restrict__ WTh,
    const _Float16* __restrict__ WTl, const float* __restrict__ bias,
    Tout* __restrict__ C, int M_A, int M_C, int NC)
{
    __shared__ _Float16 As_hi[128 * LSTR];
    __shared__ _Float16 As_lo[(SPLIT_A ? 128 : 1) * LSTR];
    __shared__ _Float16 Ws_hi[BN * LSTR];
    __shared__ _Float16 Ws_lo[BN * LSTR];

    int tid = threadIdx.x;
    int lane = tid & 63;
    int w = tid >> 6;
    int q = lane >> 4;          // quad 0..3
    int r16 = lane & 15;
    int m0 = blockIdx.x * 128;
    int n0 = blockIdx.y * BN;

    constexpr int MT = (BN == 128) ? 4 : 2;
    int wm = (BN == 128) ? (w & 1) * 64 : w * 32;
    int wn = (BN == 128) ? (w >> 1) * 64 : 0;

    f32x4 acc[MT][4];
#pragma unroll
    for (int mt = 0; mt < MT; ++mt)
#pragma unroll
        for (int nt = 0; nt < 4; ++nt) acc[mt][nt] = (f32x4){0.f, 0.f, 0.f, 0.f};

    for (int k0 = 0; k0 < 256; k0 += 32) {
        // ---- stage A tile (128 x 32) ----
        if (SPLIT_A) {
            const float* A = (const float*)Av;
#pragma unroll
            for (int p = 0; p < 4; ++p) {
                int idx = tid + p * 256;          // 1024 float4 chunks
                int m = idx >> 3, kc = idx & 7;
                int gm = m0 + m;
                float4 av = make_float4(0.f, 0.f, 0.f, 0.f);
                if (gm < M_A) av = *(const float4*)&A[(size_t)gm * 256 + k0 + kc * 4];
                half4 hi, lo;
                hi.x = (_Float16)av.x; lo.x = (_Float16)(av.x - (float)hi.x);
                hi.y = (_Float16)av.y; lo.y = (_Float16)(av.y - (float)hi.y);
                hi.z = (_Float16)av.z; lo.z = (_Float16)(av.z - (float)hi.z);
                hi.w = (_Float16)av.w; lo.w = (_Float16)(av.w - (float)hi.w);
                *(half4*)&As_hi[m * LSTR + kc * 4] = hi;
                *(half4*)&As_lo[m * LSTR + kc * 4] = lo;
            }
        } else {
            const _Float16* A = (const _Float16*)Av;
#pragma unroll
            for (int p = 0; p < 2; ++p) {
                int idx = tid + p * 256;          // 512 chunks of 8 halves
                int m = idx >> 2, kc = idx & 3;
                half8 av = *(const half8*)&A[(size_t)(m0 + m) * 256 + k0 + kc * 8];
                *(half8*)&As_hi[m * LSTR + kc * 8] = av;
            }
        }
        // ---- stage W tile (BN x 32, hi+lo) ----
#pragma unroll
        for (int p = 0; p < BN / 64; ++p) {
            int idx = tid + p * 256;
            int n = idx >> 2, kc = idx & 3;
            *(half8*)&Ws_hi[n * LSTR + kc * 8] = *(const half8*)&WTh[(size_t)(n0 + n) * 256 + k0 + kc * 8];
            *(half8*)&Ws_lo[n * LSTR + kc * 8] = *(const half8*)&WTl[(size_t)(n0 + n) * 256 + k0 + kc * 8];
        }
        __syncthreads();

        // ---- fragments ----
        half8 af_h[MT], af_l[MT], wf_h[4], wf_l[4];
#pragma unroll
        for (int mt = 0; mt < MT; ++mt) {
            int mrow = wm + mt * 16 + r16;
            af_h[mt] = *(const half8*)&As_hi[mrow * LSTR + q * 8];
            if (SPLIT_A) af_l[mt] = *(const half8*)&As_lo[mrow * LSTR + q * 8];
        }
#pragma unroll
        for (int nt = 0; nt < 4; ++nt) {
            int nrow = wn + nt * 16 + r16;
            wf_h[nt] = *(const half8*)&Ws_hi[nrow * LSTR + q * 8];
            wf_l[nt] = *(const half8*)&Ws_lo[nrow * LSTR + q * 8];
        }
        // ---- MFMA ----
#pragma unroll
        for (int mt = 0; mt < MT; ++mt)
#pragma unroll
            for (int nt = 0; nt < 4; ++nt) {
                acc[mt][nt] = mfma16(af_h[mt], wf_h[nt], acc[mt][nt]);
                if (SPLIT_A) acc[mt][nt] = mfma16(af_l[mt], wf_h[nt], acc[mt][nt]);
                acc[mt][nt] = mfma16(af_h[mt], wf_l[nt], acc[mt][nt]);
            }
        __syncthreads();
    }

    // ---- epilogue: bias (+ tanh) -> store (C layout: col=lane&15, row=quad*4+reg) ----
#pragma unroll
    for (int nt = 0; nt < 4; ++nt) {
        float b = bias[n0 + wn + nt * 16 + r16];
        int gc = n0 + wn + nt * 16 + r16;
#pragma unroll
        for (int mt = 0; mt < MT; ++mt) {
#pragma unroll
            for (int r = 0; r < 4; ++r) {
                int gm = m0 + wm + mt * 16 + q * 4 + r;
                float v = acc[mt][nt][r] + b;
                if (TANH) v = tanhf(v);
                if (gm < M_C) C[(size_t)gm * NC + gc] = (Tout)v;
            }
        }
    }
}

extern "C" void kernel_launch(void* const* d_in, const int* in_sizes, int n_in,
                              void* d_out, int out_size, void* d_ws, size_t ws_size,
                              hipStream_t stream) {
    const float* x      = (const float*)d_in[0];
    const int*   erows  = (const int*)d_in[1];
    const int*   ecols  = (const int*)d_in[2];
    const float* evals  = (const float*)d_in[3];
    const float* gamma  = (const float*)d_in[4];
    const float* beta   = (const float*)d_in[5];
    const float* w_in   = (const float*)d_in[6];
    const float* b_in   = (const float*)d_in[7];
    const float* w_conv = (const float*)d_in[8];
    const float* b_conv = (const float*)d_in[9];
    const float* w_out  = (const float*)d_in[10];
    const float* b_out  = (const float*)d_in[11];
    float* out = (float*)d_out;

    char* ws = (char*)d_ws;
    size_t off = 0;
    auto alloc = [&](size_t bytes) -> void* {
        void* p = ws + off;
        off = (off + bytes + 255) & ~(size_t)255;
        return p;
    };
    _Float16* h1   = (_Float16*)alloc((size_t)NNP * DD * 2);
    _Float16* h2   = (_Float16*)alloc((size_t)NNP * DD * 2);
    int2*  edges = (int2*) alloc((size_t)EE * 8);
    int*   rp    = (int*)  alloc((size_t)(NN + 1) * 4);
    int*   cnt   = (int*)  alloc((size_t)NN * 4);
    int*   cur   = (int*)  alloc((size_t)NN * 4);
    float* stats = (float*)alloc(2 * DD * 4);
    int*   bsums = (int*)  alloc(128 * 4);
    _Float16* wt1h = (_Float16*)alloc((size_t)DD * DD * 2);
    _Float16* wt1l = (_Float16*)alloc((size_t)DD * DD * 2);
    _Float16* wt2h = (_Float16*)alloc((size_t)DD * DD * 2);
    _Float16* wt2l = (_Float16*)alloc((size_t)DD * DD * 2);
    _Float16* wt3h = (_Float16*)alloc((size_t)DOUTC * DD * 2);
    _Float16* wt3l = (_Float16*)alloc((size_t)DOUTC * DD * 2);
    float* bfold = (float*)alloc(DD * 4);

    hipMemsetAsync(cnt,   0, (size_t)NN * 4, stream);
    hipMemsetAsync(cur,   0, (size_t)NN * 4, stream);
    hipMemsetAsync(stats, 0, 2 * DD * 4, stream);

    // CSR build
    hist_kernel<<<(EE + 255) / 256, 256, 0, stream>>>(erows, cnt);
    int nb = (NN + 1023) / 1024;   // 98
    scan1_kernel<<<nb, 256, 0, stream>>>(cnt, rp, bsums, NN);
    scan2_kernel<<<1, 256, 0, stream>>>(bsums, nb);
    scan3_kernel<<<nb, 256, 0, stream>>>(rp, bsums, NN);
    scatter_kernel<<<(EE + 255) / 256, 256, 0, stream>>>(erows, ecols, evals, rp, cur, edges);

    // BN stats + weight prep
    col_stats_kernel<<<(NN + 255) / 256, 256, 0, stream>>>(x, stats);
    fold_bias_kernel<<<1, 256, 0, stream>>>(stats, gamma, beta, w_in, b_in, bfold);
    split_w1_kernel<<<DD, DD, 0, stream>>>(stats, gamma, w_in, wt1h, wt1l);
    split_w_kernel<<<DD, DD, 0, stream>>>(w_conv, DD, wt2h, wt2l);
    split_w_kernel<<<DD, DOUTC, 0, stream>>>(w_out, DOUTC, wt3h, wt3l);

    dim3 g2(NNP / 128, 2), g1(NNP / 128, 1);
    // GEMM1: fp32 A (split) -> tanh -> fp16 h1
    gemm_mfma<true, true, _Float16, 128><<<g2, 256, 0, stream>>>(
        x, wt1h, wt1l, bfold, h1, NN, NNP, DD);

    // 4 spmm hops
    spmm_kernel<<<NN / 4, 256, 0, stream>>>(rp, edges, (const __half*)h1, (__half*)h2);
    spmm_kernel<<<NN / 4, 256, 0, stream>>>(rp, edges, (const __half*)h2, (__half*)h1);
    spmm_kernel<<<NN / 4, 256, 0, stream>>>(rp, edges, (const __half*)h1, (__half*)h2);
    spmm_kernel<<<NN / 4, 256, 0, stream>>>(rp, edges, (const __half*)h2, (__half*)h1);

    // GEMM2: fp16 A -> tanh -> fp16 h2
    gemm_mfma<false, true, _Float16, 128><<<g2, 256, 0, stream>>>(
        h1, wt2h, wt2l, b_conv, h2, NNP, NNP, DD);
    // GEMM3: fp16 A -> fp32 logits
    gemm_mfma<false, false, float, 64><<<g1, 256, 0, stream>>>(
        h2, wt3h, wt3l, b_out, out, NNP, NN, DOUTC);
}

// Round 4
// 1634.240 us; speedup vs baseline: 1.7377x; 1.0225x over previous
//
#include <hip/hip_runtime.h>
#include <hip/hip_fp16.h>

#define NN   100000
#define NNP  100096          // 782 * 128, padded row count for hop/GEMM buffers
#define EE   3200000
#define DD   256
#define DOUTC 64
#define LSTR 40              // LDS row stride in halves (80 B, 16B-aligned, 2-way bank alias = free)

typedef _Float16 half8 __attribute__((ext_vector_type(8)));
typedef _Float16 half4 __attribute__((ext_vector_type(4)));
typedef float    f32x4 __attribute__((ext_vector_type(4)));

__device__ inline f32x4 mfma16(half8 a, half8 b, f32x4 c) {
    return __builtin_amdgcn_mfma_f32_16x16x32_f16(a, b, c, 0, 0, 0);
}

// ---------------- BN column stats: sum and sumsq per column ----------------
__global__ void col_stats_kernel(const float* __restrict__ x, float* __restrict__ stats) {
    int t = threadIdx.x;            // column 0..255
    int r0 = blockIdx.x * 256;
    int r1 = min(r0 + 256, NN);
    float s = 0.f, s2 = 0.f;
    for (int r = r0; r < r1; ++r) {
        float v = x[(size_t)r * DD + t];
        s += v; s2 += v * v;
    }
    atomicAdd(&stats[t], s);
    atomicAdd(&stats[DD + t], s2);
}

// ---------------- fold BN bias: bfold = b_in + sum_j sb[j] * w_in[j][:] ----------------
__global__ void fold_bias_kernel(const float* __restrict__ stats,
                                 const float* __restrict__ gamma,
                                 const float* __restrict__ beta,
                                 const float* __restrict__ w_in,
                                 const float* __restrict__ b_in,
                                 float* __restrict__ bfold) {
    __shared__ float sb[DD];
    int t = threadIdx.x;
    float mean = stats[t] * (1.0f / NN);
    float var  = stats[DD + t] * (1.0f / NN) - mean * mean;
    float a = gamma[t] * rsqrtf(var + 1e-5f);
    sb[t] = beta[t] - mean * a;
    __syncthreads();
    float acc = 0.f;
    for (int j = 0; j < DD; ++j) acc += sb[j] * w_in[j * DD + t];
    bfold[t] = b_in[t] + acc;
}

// ---------------- split W (BN-scaled) into transposed hi/lo fp16: WT[n][k] ----------------
__global__ void split_w1_kernel(const float* __restrict__ stats,
                                const float* __restrict__ gamma,
                                const float* __restrict__ w_in,
                                _Float16* __restrict__ wth, _Float16* __restrict__ wtl) {
    int k = blockIdx.x, n = threadIdx.x;
    float mean = stats[k] * (1.0f / NN);
    float var  = stats[DD + k] * (1.0f / NN) - mean * mean;
    float a = gamma[k] * rsqrtf(var + 1e-5f);
    float v = a * w_in[(size_t)k * DD + n];
    _Float16 hi = (_Float16)v;
    _Float16 lo = (_Float16)(v - (float)hi);
    wth[(size_t)n * DD + k] = hi;
    wtl[(size_t)n * DD + k] = lo;
}

__global__ void split_w_kernel(const float* __restrict__ w, int ncols,
                               _Float16* __restrict__ wth, _Float16* __restrict__ wtl) {
    int k = blockIdx.x, n = threadIdx.x;   // w is [256][ncols]
    float v = w[(size_t)k * ncols + n];
    _Float16 hi = (_Float16)v;
    _Float16 lo = (_Float16)(v - (float)hi);
    wth[(size_t)n * DD + k] = hi;
    wtl[(size_t)n * DD + k] = lo;
}

// ---------------- CSR build (rank-based: one atomic per edge total) ----------------
__global__ void hist_kernel(const int* __restrict__ rows, int* __restrict__ cnt,
                            int* __restrict__ rank) {
    int e = blockIdx.x * blockDim.x + threadIdx.x;
    if (e < EE) rank[e] = atomicAdd(&cnt[rows[e]], 1);
}

__global__ void scan1_kernel(const int* __restrict__ in, int* __restrict__ out,
                             int* __restrict__ bsums, int n) {
    __shared__ int s[256];
    int t = threadIdx.x;
    int base = blockIdx.x * 1024;
    int v[4]; int local = 0;
    for (int i = 0; i < 4; ++i) {
        int idx = base + t * 4 + i;
        v[i] = (idx < n) ? in[idx] : 0;
        local += v[i];
    }
    s[t] = local;
    __syncthreads();
    for (int off = 1; off < 256; off <<= 1) {
        int xv = 0;
        if (t >= off) xv = s[t - off];
        __syncthreads();
        if (t >= off) s[t] += xv;
        __syncthreads();
    }
    int excl = s[t] - local;
    if (t == 255) bsums[blockIdx.x] = s[255];
    int run = excl;
    for (int i = 0; i < 4; ++i) {
        int idx = base + t * 4 + i;
        if (idx < n) out[idx] = run;
        run += v[i];
    }
}

__global__ void scan2_kernel(int* __restrict__ bsums, int nb) {
    __shared__ int s[256];
    int t = threadIdx.x;
    int v = (t < nb) ? bsums[t] : 0;
    s[t] = v;
    __syncthreads();
    for (int off = 1; off < 256; off <<= 1) {
        int xv = 0;
        if (t >= off) xv = s[t - off];
        __syncthreads();
        if (t >= off) s[t] += xv;
        __syncthreads();
    }
    if (t < nb) bsums[t] = s[t] - v;   // exclusive
}

__global__ void scan3_kernel(int* __restrict__ out, const int* __restrict__ bsums, int n) {
    int t = threadIdx.x;
    int base = blockIdx.x * 1024;
    int add = bsums[blockIdx.x];
    for (int i = 0; i < 4; ++i) {
        int idx = base + t * 4 + i;
        if (idx < n) out[idx] += add;
    }
    if (blockIdx.x == 0 && t == 0) out[n] = EE;
}

__global__ void scatter_kernel(const int* __restrict__ rows, const int* __restrict__ cols,
                               const float* __restrict__ vals, const int* __restrict__ rp,
                               const int* __restrict__ rank, int2* __restrict__ edges) {
    int e = blockIdx.x * blockDim.x + threadIdx.x;
    if (e >= EE) return;
    int r = __builtin_nontemporal_load(&rows[e]);
    int c = __builtin_nontemporal_load(&cols[e]);
    float v = __builtin_nontemporal_load(&vals[e]);
    int rk = __builtin_nontemporal_load(&rank[e]);
    int pos = rp[r] + rk;
    edges[pos] = make_int2(c, __float_as_int(v));
}

// ---------------- spmm, feature-half pass (fp16 storage, fp32 accum) ----------------
// Pass ph gathers feature-half ph (128 feats = 256 B/row). One wave per row;
// 4 edge slots x 16 lanes; each lane loads 16 B (8 fp16). Unroll 2 -> 8 edges in flight.
__global__ __launch_bounds__(256) void spmm_kernel(
        const int* __restrict__ rp, const int2* __restrict__ edges,
        const __half* __restrict__ xin, __half* __restrict__ xout, int ph) {
    int tid = threadIdx.x;
    int lane = tid & 63;
    int sub = lane >> 4;         // edge slot 0..3
    int sl = lane & 15;          // feature chunk (8 halves each)
    int r = __builtin_amdgcn_readfirstlane(blockIdx.x * 4 + (tid >> 6));
    int e0 = rp[r], e1 = rp[r + 1];
    const float4* xi = (const float4*)xin;   // 32 chunks/row; this pass uses [ph*16, ph*16+16)
    const long long* epk = (const long long*)edges;
    int cbase = ph * 16 + sl;

    float acc[8] = {0.f,0.f,0.f,0.f,0.f,0.f,0.f,0.f};

    int base = e0;
    for (; base + 8 <= e1; base += 8) {
        long long p0 = __builtin_nontemporal_load(&epk[base + sub]);
        long long p1 = __builtin_nontemporal_load(&epk[base + 4 + sub]);
        int c0 = (int)(unsigned int)p0, c1 = (int)(unsigned int)p1;
        float v0 = __int_as_float((int)(p0 >> 32));
        float v1 = __int_as_float((int)(p1 >> 32));
        float4 x0 = xi[(size_t)c0 * 32 + cbase];
        float4 x1 = xi[(size_t)c1 * 32 + cbase];
        {
            const __half2* hp = (const __half2*)&x0;
            float2 f0 = __half22float2(hp[0]);
            float2 f1 = __half22float2(hp[1]);
            float2 f2 = __half22float2(hp[2]);
            float2 f3 = __half22float2(hp[3]);
            acc[0] += v0*f0.x; acc[1] += v0*f0.y;
            acc[2] += v0*f1.x; acc[3] += v0*f1.y;
            acc[4] += v0*f2.x; acc[5] += v0*f2.y;
            acc[6] += v0*f3.x; acc[7] += v0*f3.y;
        }
        {
            const __half2* hp = (const __half2*)&x1;
            float2 f0 = __half22float2(hp[0]);
            float2 f1 = __half22float2(hp[1]);
            float2 f2 = __half22float2(hp[2]);
            float2 f3 = __half22float2(hp[3]);
            acc[0] += v1*f0.x; acc[1] += v1*f0.y;
            acc[2] += v1*f1.x; acc[3] += v1*f1.y;
            acc[4] += v1*f2.x; acc[5] += v1*f2.y;
            acc[6] += v1*f3.x; acc[7] += v1*f3.y;
        }
    }
    if (base < e1) {             // tail: 1..7 edges
#pragma unroll
        for (int i = 0; i < 2; ++i) {
            int idx = base + 4*i + sub;
            bool valid = idx < e1;
            int idxc = valid ? idx : e0;
            long long p = epk[idxc];
            int c = (int)(unsigned int)p;
            float v = valid ? __int_as_float((int)(p >> 32)) : 0.f;
            float4 xv = xi[(size_t)c * 32 + cbase];
            const __half2* hp = (const __half2*)&xv;
            float2 f0 = __half22float2(hp[0]);
            float2 f1 = __half22float2(hp[1]);
            float2 f2 = __half22float2(hp[2]);
            float2 f3 = __half22float2(hp[3]);
            acc[0] += v*f0.x; acc[1] += v*f0.y;
            acc[2] += v*f1.x; acc[3] += v*f1.y;
            acc[4] += v*f2.x; acc[5] += v*f2.y;
            acc[6] += v*f3.x; acc[7] += v*f3.y;
        }
    }
    // reduce across the 4 edge slots
#pragma unroll
    for (int j = 0; j < 8; ++j) {
        acc[j] += __shfl_xor(acc[j], 16, 64);
        acc[j] += __shfl_xor(acc[j], 32, 64);
    }
    if (sub == 0) {
        union { __half h[8]; f32x4 f; } u;
#pragma unroll
        for (int j = 0; j < 8; ++j) u.h[j] = __float2half_rn(acc[j]);
        __builtin_nontemporal_store(u.f, (f32x4*)&((float4*)xout)[(size_t)r * 32 + cbase]);
    }
}

// ---------------- MFMA GEMM with split-fp16 precision ----------------
template<bool SPLIT_A, bool TANH, typename Tout, int BN>
__global__ __launch_bounds__(256) void gemm_mfma(
    const void* __restrict__ Av, const _Float16* __restrict__ WTh,
    const _Float16* __restrict__ WTl, const float* __restrict__ bias,
    Tout* __restrict__ C, int M_A, int M_C, int NC)
{
    __shared__ _Float16 As_hi[128 * LSTR];
    __shared__ _Float16 As_lo[(SPLIT_A ? 128 : 1) * LSTR];
    __shared__ _Float16 Ws_hi[BN * LSTR];
    __shared__ _Float16 Ws_lo[BN * LSTR];

    int tid = threadIdx.x;
    int lane = tid & 63;
    int w = tid >> 6;
    int q = lane >> 4;          // quad 0..3
    int r16 = lane & 15;
    int m0 = blockIdx.x * 128;
    int n0 = blockIdx.y * BN;

    constexpr int MT = (BN == 128) ? 4 : 2;
    int wm = (BN == 128) ? (w & 1) * 64 : w * 32;
    int wn = (BN == 128) ? (w >> 1) * 64 : 0;

    f32x4 acc[MT][4];
#pragma unroll
    for (int mt = 0; mt < MT; ++mt)
#pragma unroll
        for (int nt = 0; nt < 4; ++nt) acc[mt][nt] = (f32x4){0.f, 0.f, 0.f, 0.f};

    for (int k0 = 0; k0 < 256; k0 += 32) {
        // ---- stage A tile (128 x 32) ----
        if (SPLIT_A) {
            const float* A = (const float*)Av;
#pragma unroll
            for (int p = 0; p < 4; ++p) {
                int idx = tid + p * 256;          // 1024 float4 chunks
                int m = idx >> 3, kc = idx & 7;
                int gm = m0 + m;
                float4 av = make_float4(0.f, 0.f, 0.f, 0.f);
                if (gm < M_A) av = *(const float4*)&A[(size_t)gm * 256 + k0 + kc * 4];
                half4 hi, lo;
                hi.x = (_Float16)av.x; lo.x = (_Float16)(av.x - (float)hi.x);
                hi.y = (_Float16)av.y; lo.y = (_Float16)(av.y - (float)hi.y);
                hi.z = (_Float16)av.z; lo.z = (_Float16)(av.z - (float)hi.z);
                hi.w = (_Float16)av.w; lo.w = (_Float16)(av.w - (float)hi.w);
                *(half4*)&As_hi[m * LSTR + kc * 4] = hi;
                *(half4*)&As_lo[m * LSTR + kc * 4] = lo;
            }
        } else {
            const _Float16* A = (const _Float16*)Av;
#pragma unroll
            for (int p = 0; p < 2; ++p) {
                int idx = tid + p * 256;          // 512 chunks of 8 halves
                int m = idx >> 2, kc = idx & 3;
                half8 av = *(const half8*)&A[(size_t)(m0 + m) * 256 + k0 + kc * 8];
                *(half8*)&As_hi[m * LSTR + kc * 8] = av;
            }
        }
        // ---- stage W tile (BN x 32, hi+lo) ----
#pragma unroll
        for (int p = 0; p < BN / 64; ++p) {
            int idx = tid + p * 256;
            int n = idx >> 2, kc = idx & 3;
            *(half8*)&Ws_hi[n * LSTR + kc * 8] = *(const half8*)&WTh[(size_t)(n0 + n) * 256 + k0 + kc * 8];
            *(half8*)&Ws_lo[n * LSTR + kc * 8] = *(const half8*)&WTl[(size_t)(n0 + n) * 256 + k0 + kc * 8];
        }
        __syncthreads();

        // ---- fragments ----
        half8 af_h[MT], af_l[MT], wf_h[4], wf_l[4];
#pragma unroll
        for (int mt = 0; mt < MT; ++mt) {
            int mrow = wm + mt * 16 + r16;
            af_h[mt] = *(const half8*)&As_hi[mrow * LSTR + q * 8];
            if (SPLIT_A) af_l[mt] = *(const half8*)&As_lo[mrow * LSTR + q * 8];
        }
#pragma unroll
        for (int nt = 0; nt < 4; ++nt) {
            int nrow = wn + nt * 16 + r16;
            wf_h[nt] = *(const half8*)&Ws_hi[nrow * LSTR + q * 8];
            wf_l[nt] = *(const half8*)&Ws_lo[nrow * LSTR + q * 8];
        }
        // ---- MFMA ----
#pragma unroll
        for (int mt = 0; mt < MT; ++mt)
#pragma unroll
            for (int nt = 0; nt < 4; ++nt) {
                acc[mt][nt] = mfma16(af_h[mt], wf_h[nt], acc[mt][nt]);
                if (SPLIT_A) acc[mt][nt] = mfma16(af_l[mt], wf_h[nt], acc[mt][nt]);
                acc[mt][nt] = mfma16(af_h[mt], wf_l[nt], acc[mt][nt]);
            }
        __syncthreads();
    }

    // ---- epilogue: bias (+ tanh) -> store (C layout: col=lane&15, row=quad*4+reg) ----
#pragma unroll
    for (int nt = 0; nt < 4; ++nt) {
        float b = bias[n0 + wn + nt * 16 + r16];
        int gc = n0 + wn + nt * 16 + r16;
#pragma unroll
        for (int mt = 0; mt < MT; ++mt) {
#pragma unroll
            for (int r = 0; r < 4; ++r) {
                int gm = m0 + wm + mt * 16 + q * 4 + r;
                float v = acc[mt][nt][r] + b;
                if (TANH) v = tanhf(v);
                if (gm < M_C) C[(size_t)gm * NC + gc] = (Tout)v;
            }
        }
    }
}

extern "C" void kernel_launch(void* const* d_in, const int* in_sizes, int n_in,
                              void* d_out, int out_size, void* d_ws, size_t ws_size,
                              hipStream_t stream) {
    const float* x      = (const float*)d_in[0];
    const int*   erows  = (const int*)d_in[1];
    const int*   ecols  = (const int*)d_in[2];
    const float* evals  = (const float*)d_in[3];
    const float* gamma  = (const float*)d_in[4];
    const float* beta   = (const float*)d_in[5];
    const float* w_in   = (const float*)d_in[6];
    const float* b_in   = (const float*)d_in[7];
    const float* w_conv = (const float*)d_in[8];
    const float* b_conv = (const float*)d_in[9];
    const float* w_out  = (const float*)d_in[10];
    const float* b_out  = (const float*)d_in[11];
    float* out = (float*)d_out;

    char* ws = (char*)d_ws;
    size_t off = 0;
    auto alloc = [&](size_t bytes) -> void* {
        void* p = ws + off;
        off = (off + bytes + 255) & ~(size_t)255;
        return p;
    };
    _Float16* h1   = (_Float16*)alloc((size_t)NNP * DD * 2);
    _Float16* h2   = (_Float16*)alloc((size_t)NNP * DD * 2);
    int2*  edges = (int2*) alloc((size_t)EE * 8);
    int*   rank  = (int*)  alloc((size_t)EE * 4);
    int*   rp    = (int*)  alloc((size_t)(NN + 1) * 4);
    int*   cnt   = (int*)  alloc((size_t)NN * 4);
    float* stats = (float*)alloc(2 * DD * 4);
    int*   bsums = (int*)  alloc(128 * 4);
    _Float16* wt1h = (_Float16*)alloc((size_t)DD * DD * 2);
    _Float16* wt1l = (_Float16*)alloc((size_t)DD * DD * 2);
    _Float16* wt2h = (_Float16*)alloc((size_t)DD * DD * 2);
    _Float16* wt2l = (_Float16*)alloc((size_t)DD * DD * 2);
    _Float16* wt3h = (_Float16*)alloc((size_t)DOUTC * DD * 2);
    _Float16* wt3l = (_Float16*)alloc((size_t)DOUTC * DD * 2);
    float* bfold = (float*)alloc(DD * 4);

    hipMemsetAsync(cnt,   0, (size_t)NN * 4, stream);
    hipMemsetAsync(stats, 0, 2 * DD * 4, stream);

    // CSR build (rank-based)
    hist_kernel<<<(EE + 255) / 256, 256, 0, stream>>>(erows, cnt, rank);
    int nb = (NN + 1023) / 1024;   // 98
    scan1_kernel<<<nb, 256, 0, stream>>>(cnt, rp, bsums, NN);
    scan2_kernel<<<1, 256, 0, stream>>>(bsums, nb);
    scan3_kernel<<<nb, 256, 0, stream>>>(rp, bsums, NN);
    scatter_kernel<<<(EE + 255) / 256, 256, 0, stream>>>(erows, ecols, evals, rp, rank, edges);

    // BN stats + weight prep
    col_stats_kernel<<<(NN + 255) / 256, 256, 0, stream>>>(x, stats);
    fold_bias_kernel<<<1, 256, 0, stream>>>(stats, gamma, beta, w_in, b_in, bfold);
    split_w1_kernel<<<DD, DD, 0, stream>>>(stats, gamma, w_in, wt1h, wt1l);
    split_w_kernel<<<DD, DD, 0, stream>>>(w_conv, DD, wt2h, wt2l);
    split_w_kernel<<<DD, DOUTC, 0, stream>>>(w_out, DOUTC, wt3h, wt3l);

    dim3 g2(NNP / 128, 2), g1(NNP / 128, 1);
    // GEMM1: fp32 A (split) -> tanh -> fp16 h1
    gemm_mfma<true, true, _Float16, 128><<<g2, 256, 0, stream>>>(
        x, wt1h, wt1l, bfold, h1, NN, NNP, DD);

    // 4 spmm hops, 2 feature-half passes each
    spmm_kernel<<<NN / 4, 256, 0, stream>>>(rp, edges, (const __half*)h1, (__half*)h2, 0);
    spmm_kernel<<<NN / 4, 256, 0, stream>>>(rp, edges, (const __half*)h1, (__half*)h2, 1);
    spmm_kernel<<<NN / 4, 256, 0, stream>>>(rp, edges, (const __half*)h2, (__half*)h1, 0);
    spmm_kernel<<<NN / 4, 256, 0, stream>>>(rp, edges, (const __half*)h2, (__half*)h1, 1);
    spmm_kernel<<<NN / 4, 256, 0, stream>>>(rp, edges, (const __half*)h1, (__half*)h2, 0);
    spmm_kernel<<<NN / 4, 256, 0, stream>>>(rp, edges, (const __half*)h1, (__half*)h2, 1);
    spmm_kernel<<<NN / 4, 256, 0, stream>>>(rp, edges, (const __half*)h2, (__half*)h1, 0);
    spmm_kernel<<<NN / 4, 256, 0, stream>>>(rp, edges, (const __half*)h2, (__half*)h1, 1);

    // GEMM2: fp16 A -> tanh -> fp16 h2
    gemm_mfma<false, true, _Float16, 128><<<g2, 256, 0, stream>>>(
        h1, wt2h, wt2l, b_conv, h2, NNP, NNP, DD);
    // GEMM3: fp16 A -> fp32 logits
    gemm_mfma<false, false, float, 64><<<g1, 256, 0, stream>>>(
        h2, wt3h, wt3l, b_out, out, NNP, NN, DOUTC);
}

// Round 5
// 1540.535 us; speedup vs baseline: 1.8434x; 1.0608x over previous
//
#include <hip/hip_runtime.h>
#include <hip/hip_fp16.h>

#define NN   100000
#define NNP  100096          // 782 * 128, padded row count for hop/GEMM buffers
#define EE   3200000
#define DD   256
#define DOUTC 64
#define LSTR 40              // LDS row stride in halves (80 B, 16B-aligned, 2-way bank alias = free)

#define NBK  782             // buckets of 128 rows (row >> 7); 782*128 = 100096 >= NN
#define PB   512             // partition blocks for count/scatter
#define CHUNK 6250           // edges per partition block; 512*6250 = EE exactly

typedef _Float16 half8 __attribute__((ext_vector_type(8)));
typedef _Float16 half4 __attribute__((ext_vector_type(4)));
typedef float    f32x4 __attribute__((ext_vector_type(4)));

__device__ inline f32x4 mfma16(half8 a, half8 b, f32x4 c) {
    return __builtin_amdgcn_mfma_f32_16x16x32_f16(a, b, c, 0, 0, 0);
}

// ---------------- BN column stats: sum and sumsq per column ----------------
__global__ void col_stats_kernel(const float* __restrict__ x, float* __restrict__ stats) {
    int t = threadIdx.x;            // column 0..255
    int r0 = blockIdx.x * 256;
    int r1 = min(r0 + 256, NN);
    float s = 0.f, s2 = 0.f;
    for (int r = r0; r < r1; ++r) {
        float v = x[(size_t)r * DD + t];
        s += v; s2 += v * v;
    }
    atomicAdd(&stats[t], s);
    atomicAdd(&stats[DD + t], s2);
}

// ---------------- fold BN bias: bfold = b_in + sum_j sb[j] * w_in[j][:] ----------------
__global__ void fold_bias_kernel(const float* __restrict__ stats,
                                 const float* __restrict__ gamma,
                                 const float* __restrict__ beta,
                                 const float* __restrict__ w_in,
                                 const float* __restrict__ b_in,
                                 float* __restrict__ bfold) {
    __shared__ float sb[DD];
    int t = threadIdx.x;
    float mean = stats[t] * (1.0f / NN);
    float var  = stats[DD + t] * (1.0f / NN) - mean * mean;
    float a = gamma[t] * rsqrtf(var + 1e-5f);
    sb[t] = beta[t] - mean * a;
    __syncthreads();
    float acc = 0.f;
    for (int j = 0; j < DD; ++j) acc += sb[j] * w_in[j * DD + t];
    bfold[t] = b_in[t] + acc;
}

// ---------------- split W (BN-scaled) into transposed hi/lo fp16: WT[n][k] ----------------
__global__ void split_w1_kernel(const float* __restrict__ stats,
                                const float* __restrict__ gamma,
                                const float* __restrict__ w_in,
                                _Float16* __restrict__ wth, _Float16* __restrict__ wtl) {
    int k = blockIdx.x, n = threadIdx.x;
    float mean = stats[k] * (1.0f / NN);
    float var  = stats[DD + k] * (1.0f / NN) - mean * mean;
    float a = gamma[k] * rsqrtf(var + 1e-5f);
    float v = a * w_in[(size_t)k * DD + n];
    _Float16 hi = (_Float16)v;
    _Float16 lo = (_Float16)(v - (float)hi);
    wth[(size_t)n * DD + k] = hi;
    wtl[(size_t)n * DD + k] = lo;
}

__global__ void split_w_kernel(const float* __restrict__ w, int ncols,
                               _Float16* __restrict__ wth, _Float16* __restrict__ wtl) {
    int k = blockIdx.x, n = threadIdx.x;   // w is [256][ncols]
    float v = w[(size_t)k * ncols + n];
    _Float16 hi = (_Float16)v;
    _Float16 lo = (_Float16)(v - (float)hi);
    wth[(size_t)n * DD + k] = hi;
    wtl[(size_t)n * DD + k] = lo;
}

// ================= CSR build, LDS-aggregated (no device-scope atomics) =================
// A: per-partition-block bucket counts -> Cm[PB][NBK]
__global__ __launch_bounds__(256) void bucket_count_kernel(
        const int* __restrict__ rows, int* __restrict__ Cm) {
    __shared__ int bins[NBK];
    int t = threadIdx.x;
    for (int i = t; i < NBK; i += 256) bins[i] = 0;
    __syncthreads();
    int base = blockIdx.x * CHUNK;
    for (int e = base + t; e < base + CHUNK; e += 256) {
        int r = __builtin_nontemporal_load(&rows[e]);
        atomicAdd(&bins[r >> 7], 1);
    }
    __syncthreads();
    for (int i = t; i < NBK; i += 256) Cm[(size_t)blockIdx.x * NBK + i] = bins[i];
}

// B1: exclusive scan down each bucket column of Cm; totals -> Tb
__global__ __launch_bounds__(256) void scan_col_kernel(int* __restrict__ Cm,
                                                       int* __restrict__ Tb) {
    __shared__ int s[256];
    int b = blockIdx.x;
    int t = threadIdx.x;
    int v0 = Cm[(size_t)(2 * t)     * NBK + b];
    int v1 = Cm[(size_t)(2 * t + 1) * NBK + b];
    int local = v0 + v1;
    s[t] = local;
    __syncthreads();
    for (int off = 1; off < 256; off <<= 1) {
        int xv = 0;
        if (t >= off) xv = s[t - off];
        __syncthreads();
        if (t >= off) s[t] += xv;
        __syncthreads();
    }
    int excl = s[t] - local;
    Cm[(size_t)(2 * t)     * NBK + b] = excl;
    Cm[(size_t)(2 * t + 1) * NBK + b] = excl + v0;
    if (t == 255) Tb[b] = s[255];
}

// B2: exclusive scan of bucket totals -> Bb[0..NBK], Bb[NBK] = EE
__global__ __launch_bounds__(256) void scan_buckets_kernel(const int* __restrict__ Tb,
                                                           int* __restrict__ Bb) {
    __shared__ int s[256];
    int t = threadIdx.x;
    int v[4]; int local = 0;
    for (int i = 0; i < 4; ++i) {
        int idx = t * 4 + i;
        v[i] = (idx < NBK) ? Tb[idx] : 0;
        local += v[i];
    }
    s[t] = local;
    __syncthreads();
    for (int off = 1; off < 256; off <<= 1) {
        int xv = 0;
        if (t >= off) xv = s[t - off];
        __syncthreads();
        if (t >= off) s[t] += xv;
        __syncthreads();
    }
    int excl = s[t] - local;
    int run = excl;
    for (int i = 0; i < 4; ++i) {
        int idx = t * 4 + i;
        if (idx < NBK) Bb[idx] = run;
        run += v[i];
    }
    if (t == 255) Bb[NBK] = EE;
}

// C: scatter edges into bucket-contiguous ebuf, packed (rowlo<<17 | col, val)
__global__ __launch_bounds__(256) void bucket_scatter_kernel(
        const int* __restrict__ rows, const int* __restrict__ cols,
        const float* __restrict__ vals, const int* __restrict__ Cm,
        const int* __restrict__ Bb, int2* __restrict__ ebuf) {
    __shared__ int bins[NBK];
    int t = threadIdx.x;
    for (int i = t; i < NBK; i += 256) bins[i] = 0;
    __syncthreads();
    int base = blockIdx.x * CHUNK;
    for (int e = base + t; e < base + CHUNK; e += 256) {
        int r = __builtin_nontemporal_load(&rows[e]);
        int c = __builtin_nontemporal_load(&cols[e]);
        float v = __builtin_nontemporal_load(&vals[e]);
        int bkt = r >> 7;
        int lr = atomicAdd(&bins[bkt], 1);
        int pos = Bb[bkt] + Cm[(size_t)blockIdx.x * NBK + bkt] + lr;
        ebuf[pos] = make_int2(c | ((r & 127) << 17), __float_as_int(v));
    }
}

// D: per-bucket 128-row hist+scan in LDS -> rp + final row-major CSR edges
__global__ __launch_bounds__(256) void bucket_finalize_kernel(
        const int* __restrict__ Bb, const int2* __restrict__ ebuf,
        int* __restrict__ rp, int2* __restrict__ edges) {
    __shared__ int hist[128];
    __shared__ int excl[128];
    __shared__ int cur[128];
    __shared__ int sc[128];
    int b = blockIdx.x;
    int t = threadIdx.x;
    int e0 = Bb[b], e1 = Bb[b + 1];
    if (t < 128) { hist[t] = 0; cur[t] = 0; }
    __syncthreads();
    for (int e = e0 + t; e < e1; e += 256)
        atomicAdd(&hist[ebuf[e].x >> 17], 1);
    __syncthreads();
    if (t < 128) sc[t] = hist[t];
    __syncthreads();
    for (int off = 1; off < 128; off <<= 1) {
        int xv = 0;
        if (t < 128 && t >= off) xv = sc[t - off];
        __syncthreads();
        if (t < 128 && t >= off) sc[t] += xv;
        __syncthreads();
    }
    if (t < 128) {
        excl[t] = sc[t] - hist[t];
        int gr = b * 128 + t;
        if (gr < NN) rp[gr] = e0 + excl[t];
    }
    if (b == 0 && t == 0) rp[NN] = EE;
    __syncthreads();
    for (int e = e0 + t; e < e1; e += 256) {
        int2 d = ebuf[e];
        int rl = d.x >> 17;
        int lr = atomicAdd(&cur[rl], 1);
        edges[e0 + excl[rl] + lr] = make_int2(d.x & 0x1FFFF, d.y);
    }
}

// ---------------- spmm, feature-half pass (fp16 storage, fp32 accum) ----------------
__global__ __launch_bounds__(256) void spmm_kernel(
        const int* __restrict__ rp, const int2* __restrict__ edges,
        const __half* __restrict__ xin, __half* __restrict__ xout, int ph) {
    int tid = threadIdx.x;
    int lane = tid & 63;
    int sub = lane >> 4;         // edge slot 0..3
    int sl = lane & 15;          // feature chunk (8 halves each)
    int r = __builtin_amdgcn_readfirstlane(blockIdx.x * 4 + (tid >> 6));
    int e0 = rp[r], e1 = rp[r + 1];
    const float4* xi = (const float4*)xin;   // 32 chunks/row; this pass uses [ph*16, ph*16+16)
    const long long* epk = (const long long*)edges;
    int cbase = ph * 16 + sl;

    float acc[8] = {0.f,0.f,0.f,0.f,0.f,0.f,0.f,0.f};

    int base = e0;
    for (; base + 8 <= e1; base += 8) {
        long long p0 = __builtin_nontemporal_load(&epk[base + sub]);
        long long p1 = __builtin_nontemporal_load(&epk[base + 4 + sub]);
        int c0 = (int)(unsigned int)p0, c1 = (int)(unsigned int)p1;
        float v0 = __int_as_float((int)(p0 >> 32));
        float v1 = __int_as_float((int)(p1 >> 32));
        float4 x0 = xi[(size_t)c0 * 32 + cbase];
        float4 x1 = xi[(size_t)c1 * 32 + cbase];
        {
            const __half2* hp = (const __half2*)&x0;
            float2 f0 = __half22float2(hp[0]);
            float2 f1 = __half22float2(hp[1]);
            float2 f2 = __half22float2(hp[2]);
            float2 f3 = __half22float2(hp[3]);
            acc[0] += v0*f0.x; acc[1] += v0*f0.y;
            acc[2] += v0*f1.x; acc[3] += v0*f1.y;
            acc[4] += v0*f2.x; acc[5] += v0*f2.y;
            acc[6] += v0*f3.x; acc[7] += v0*f3.y;
        }
        {
            const __half2* hp = (const __half2*)&x1;
            float2 f0 = __half22float2(hp[0]);
            float2 f1 = __half22float2(hp[1]);
            float2 f2 = __half22float2(hp[2]);
            float2 f3 = __half22float2(hp[3]);
            acc[0] += v1*f0.x; acc[1] += v1*f0.y;
            acc[2] += v1*f1.x; acc[3] += v1*f1.y;
            acc[4] += v1*f2.x; acc[5] += v1*f2.y;
            acc[6] += v1*f3.x; acc[7] += v1*f3.y;
        }
    }
    if (base < e1) {             // tail: 1..7 edges
#pragma unroll
        for (int i = 0; i < 2; ++i) {
            int idx = base + 4*i + sub;
            bool valid = idx < e1;
            int idxc = valid ? idx : e0;
            long long p = epk[idxc];
            int c = (int)(unsigned int)p;
            float v = valid ? __int_as_float((int)(p >> 32)) : 0.f;
            float4 xv = xi[(size_t)c * 32 + cbase];
            const __half2* hp = (const __half2*)&xv;
            float2 f0 = __half22float2(hp[0]);
            float2 f1 = __half22float2(hp[1]);
            float2 f2 = __half22float2(hp[2]);
            float2 f3 = __half22float2(hp[3]);
            acc[0] += v*f0.x; acc[1] += v*f0.y;
            acc[2] += v*f1.x; acc[3] += v*f1.y;
            acc[4] += v*f2.x; acc[5] += v*f2.y;
            acc[6] += v*f3.x; acc[7] += v*f3.y;
        }
    }
    // reduce across the 4 edge slots
#pragma unroll
    for (int j = 0; j < 8; ++j) {
        acc[j] += __shfl_xor(acc[j], 16, 64);
        acc[j] += __shfl_xor(acc[j], 32, 64);
    }
    if (sub == 0) {
        union { __half h[8]; f32x4 f; } u;
#pragma unroll
        for (int j = 0; j < 8; ++j) u.h[j] = __float2half_rn(acc[j]);
        __builtin_nontemporal_store(u.f, (f32x4*)&((float4*)xout)[(size_t)r * 32 + cbase]);
    }
}

// ---------------- MFMA GEMM with split-fp16 precision ----------------
template<bool SPLIT_A, bool TANH, typename Tout, int BN>
__global__ __launch_bounds__(256) void gemm_mfma(
    const void* __restrict__ Av, const _Float16* __restrict__ WTh,
    const _Float16* __restrict__ WTl, const float* __restrict__ bias,
    Tout* __restrict__ C, int M_A, int M_C, int NC)
{
    __shared__ _Float16 As_hi[128 * LSTR];
    __shared__ _Float16 As_lo[(SPLIT_A ? 128 : 1) * LSTR];
    __shared__ _Float16 Ws_hi[BN * LSTR];
    __shared__ _Float16 Ws_lo[BN * LSTR];

    int tid = threadIdx.x;
    int lane = tid & 63;
    int w = tid >> 6;
    int q = lane >> 4;          // quad 0..3
    int r16 = lane & 15;
    int m0 = blockIdx.x * 128;
    int n0 = blockIdx.y * BN;

    constexpr int MT = (BN == 128) ? 4 : 2;
    int wm = (BN == 128) ? (w & 1) * 64 : w * 32;
    int wn = (BN == 128) ? (w >> 1) * 64 : 0;

    f32x4 acc[MT][4];
#pragma unroll
    for (int mt = 0; mt < MT; ++mt)
#pragma unroll
        for (int nt = 0; nt < 4; ++nt) acc[mt][nt] = (f32x4){0.f, 0.f, 0.f, 0.f};

    for (int k0 = 0; k0 < 256; k0 += 32) {
        // ---- stage A tile (128 x 32) ----
        if (SPLIT_A) {
            const float* A = (const float*)Av;
#pragma unroll
            for (int p = 0; p < 4; ++p) {
                int idx = tid + p * 256;          // 1024 float4 chunks
                int m = idx >> 3, kc = idx & 7;
                int gm = m0 + m;
                float4 av = make_float4(0.f, 0.f, 0.f, 0.f);
                if (gm < M_A) av = *(const float4*)&A[(size_t)gm * 256 + k0 + kc * 4];
                half4 hi, lo;
                hi.x = (_Float16)av.x; lo.x = (_Float16)(av.x - (float)hi.x);
                hi.y = (_Float16)av.y; lo.y = (_Float16)(av.y - (float)hi.y);
                hi.z = (_Float16)av.z; lo.z = (_Float16)(av.z - (float)hi.z);
                hi.w = (_Float16)av.w; lo.w = (_Float16)(av.w - (float)hi.w);
                *(half4*)&As_hi[m * LSTR + kc * 4] = hi;
                *(half4*)&As_lo[m * LSTR + kc * 4] = lo;
            }
        } else {
            const _Float16* A = (const _Float16*)Av;
#pragma unroll
            for (int p = 0; p < 2; ++p) {
                int idx = tid + p * 256;          // 512 chunks of 8 halves
                int m = idx >> 2, kc = idx & 3;
                half8 av = *(const half8*)&A[(size_t)(m0 + m) * 256 + k0 + kc * 8];
                *(half8*)&As_hi[m * LSTR + kc * 8] = av;
            }
        }
        // ---- stage W tile (BN x 32, hi+lo) ----
#pragma unroll
        for (int p = 0; p < BN / 64; ++p) {
            int idx = tid + p * 256;
            int n = idx >> 2, kc = idx & 3;
            *(half8*)&Ws_hi[n * LSTR + kc * 8] = *(const half8*)&WTh[(size_t)(n0 + n) * 256 + k0 + kc * 8];
            *(half8*)&Ws_lo[n * LSTR + kc * 8] = *(const half8*)&WTl[(size_t)(n0 + n) * 256 + k0 + kc * 8];
        }
        __syncthreads();

        // ---- fragments ----
        half8 af_h[MT], af_l[MT], wf_h[4], wf_l[4];
#pragma unroll
        for (int mt = 0; mt < MT; ++mt) {
            int mrow = wm + mt * 16 + r16;
            af_h[mt] = *(const half8*)&As_hi[mrow * LSTR + q * 8];
            if (SPLIT_A) af_l[mt] = *(const half8*)&As_lo[mrow * LSTR + q * 8];
        }
#pragma unroll
        for (int nt = 0; nt < 4; ++nt) {
            int nrow = wn + nt * 16 + r16;
            wf_h[nt] = *(const half8*)&Ws_hi[nrow * LSTR + q * 8];
            wf_l[nt] = *(const half8*)&Ws_lo[nrow * LSTR + q * 8];
        }
        // ---- MFMA ----
#pragma unroll
        for (int mt = 0; mt < MT; ++mt)
#pragma unroll
            for (int nt = 0; nt < 4; ++nt) {
                acc[mt][nt] = mfma16(af_h[mt], wf_h[nt], acc[mt][nt]);
                if (SPLIT_A) acc[mt][nt] = mfma16(af_l[mt], wf_h[nt], acc[mt][nt]);
                acc[mt][nt] = mfma16(af_h[mt], wf_l[nt], acc[mt][nt]);
            }
        __syncthreads();
    }

    // ---- epilogue: bias (+ tanh) -> store (C layout: col=lane&15, row=quad*4+reg) ----
#pragma unroll
    for (int nt = 0; nt < 4; ++nt) {
        float b = bias[n0 + wn + nt * 16 + r16];
        int gc = n0 + wn + nt * 16 + r16;
#pragma unroll
        for (int mt = 0; mt < MT; ++mt) {
#pragma unroll
            for (int r = 0; r < 4; ++r) {
                int gm = m0 + wm + mt * 16 + q * 4 + r;
                float v = acc[mt][nt][r] + b;
                if (TANH) v = tanhf(v);
                if (gm < M_C) C[(size_t)gm * NC + gc] = (Tout)v;
            }
        }
    }
}

extern "C" void kernel_launch(void* const* d_in, const int* in_sizes, int n_in,
                              void* d_out, int out_size, void* d_ws, size_t ws_size,
                              hipStream_t stream) {
    const float* x      = (const float*)d_in[0];
    const int*   erows  = (const int*)d_in[1];
    const int*   ecols  = (const int*)d_in[2];
    const float* evals  = (const float*)d_in[3];
    const float* gamma  = (const float*)d_in[4];
    const float* beta   = (const float*)d_in[5];
    const float* w_in   = (const float*)d_in[6];
    const float* b_in   = (const float*)d_in[7];
    const float* w_conv = (const float*)d_in[8];
    const float* b_conv = (const float*)d_in[9];
    const float* w_out  = (const float*)d_in[10];
    const float* b_out  = (const float*)d_in[11];
    float* out = (float*)d_out;

    char* ws = (char*)d_ws;
    size_t off = 0;
    auto alloc = [&](size_t bytes) -> void* {
        void* p = ws + off;
        off = (off + bytes + 255) & ~(size_t)255;
        return p;
    };
    _Float16* h1   = (_Float16*)alloc((size_t)NNP * DD * 2);
    _Float16* h2   = (_Float16*)alloc((size_t)NNP * DD * 2);
    int2*  edges = (int2*) alloc((size_t)EE * 8);
    int2*  ebuf  = (int2*) alloc((size_t)EE * 8);
    int*   Cm    = (int*)  alloc((size_t)PB * NBK * 4);
    int*   Tb    = (int*)  alloc((size_t)NBK * 4);
    int*   Bb    = (int*)  alloc((size_t)(NBK + 1) * 4);
    int*   rp    = (int*)  alloc((size_t)(NN + 1) * 4);
    float* stats = (float*)alloc(2 * DD * 4);
    _Float16* wt1h = (_Float16*)alloc((size_t)DD * DD * 2);
    _Float16* wt1l = (_Float16*)alloc((size_t)DD * DD * 2);
    _Float16* wt2h = (_Float16*)alloc((size_t)DD * DD * 2);
    _Float16* wt2l = (_Float16*)alloc((size_t)DD * DD * 2);
    _Float16* wt3h = (_Float16*)alloc((size_t)DOUTC * DD * 2);
    _Float16* wt3l = (_Float16*)alloc((size_t)DOUTC * DD * 2);
    float* bfold = (float*)alloc(DD * 4);

    hipMemsetAsync(stats, 0, 2 * DD * 4, stream);

    // CSR build: LDS-bucketed, no device-scope atomics
    bucket_count_kernel<<<PB, 256, 0, stream>>>(erows, Cm);
    scan_col_kernel<<<NBK, 256, 0, stream>>>(Cm, Tb);
    scan_buckets_kernel<<<1, 256, 0, stream>>>(Tb, Bb);
    bucket_scatter_kernel<<<PB, 256, 0, stream>>>(erows, ecols, evals, Cm, Bb, ebuf);
    bucket_finalize_kernel<<<NBK, 256, 0, stream>>>(Bb, ebuf, rp, edges);

    // BN stats + weight prep
    col_stats_kernel<<<(NN + 255) / 256, 256, 0, stream>>>(x, stats);
    fold_bias_kernel<<<1, 256, 0, stream>>>(stats, gamma, beta, w_in, b_in, bfold);
    split_w1_kernel<<<DD, DD, 0, stream>>>(stats, gamma, w_in, wt1h, wt1l);
    split_w_kernel<<<DD, DD, 0, stream>>>(w_conv, DD, wt2h, wt2l);
    split_w_kernel<<<DD, DOUTC, 0, stream>>>(w_out, DOUTC, wt3h, wt3l);

    dim3 g2(NNP / 128, 2), g1(NNP / 128, 1);
    // GEMM1: fp32 A (split) -> tanh -> fp16 h1
    gemm_mfma<true, true, _Float16, 128><<<g2, 256, 0, stream>>>(
        x, wt1h, wt1l, bfold, h1, NN, NNP, DD);

    // 4 spmm hops, 2 feature-half passes each
    spmm_kernel<<<NN / 4, 256, 0, stream>>>(rp, edges, (const __half*)h1, (__half*)h2, 0);
    spmm_kernel<<<NN / 4, 256, 0, stream>>>(rp, edges, (const __half*)h1, (__half*)h2, 1);
    spmm_kernel<<<NN / 4, 256, 0, stream>>>(rp, edges, (const __half*)h2, (__half*)h1, 0);
    spmm_kernel<<<NN / 4, 256, 0, stream>>>(rp, edges, (const __half*)h2, (__half*)h1, 1);
    spmm_kernel<<<NN / 4, 256, 0, stream>>>(rp, edges, (const __half*)h1, (__half*)h2, 0);
    spmm_kernel<<<NN / 4, 256, 0, stream>>>(rp, edges, (const __half*)h1, (__half*)h2, 1);
    spmm_kernel<<<NN / 4, 256, 0, stream>>>(rp, edges, (const __half*)h2, (__half*)h1, 0);
    spmm_kernel<<<NN / 4, 256, 0, stream>>>(rp, edges, (const __half*)h2, (__half*)h1, 1);

    // GEMM2: fp16 A -> tanh -> fp16 h2
    gemm_mfma<false, true, _Float16, 128><<<g2, 256, 0, stream>>>(
        h1, wt2h, wt2l, b_conv, h2, NNP, NNP, DD);
    // GEMM3: fp16 A -> fp32 logits
    gemm_mfma<false, false, float, 64><<<g1, 256, 0, stream>>>(
        h2, wt3h, wt3l, b_out, out, NNP, NN, DOUTC);
}

// Round 6
// 1493.690 us; speedup vs baseline: 1.9012x; 1.0314x over previous
//
#include <hip/hip_runtime.h>
#include <hip/hip_fp16.h>

#define NN   100000
#define NNP  100096          // 782 * 128, padded row count for hop/GEMM buffers
#define EE   3200000
#define DD   256
#define DOUTC 64
#define LSTR 40              // LDS row stride in halves (80 B, 16B-aligned, 2-way bank alias = free)

#define NBK  782             // buckets of 128 rows (row >> 7); 782*128 = 100096 >= NN
#define PB   512             // partition blocks for count/scatter
#define CHUNK 6250           // edges per partition block; 512*6250 = EE exactly
#define STATB 512            // col_stats blocks

typedef _Float16 half8 __attribute__((ext_vector_type(8)));
typedef _Float16 half4 __attribute__((ext_vector_type(4)));
typedef float    f32x4 __attribute__((ext_vector_type(4)));

__device__ inline f32x4 mfma16(half8 a, half8 b, f32x4 c) {
    return __builtin_amdgcn_mfma_f32_16x16x32_f16(a, b, c, 0, 0, 0);
}

// ---------------- BN column stats: sum and sumsq per column ----------------
// 512 blocks x 256 thr; lane c4 covers cols [c4*4, c4*4+4); 4 row-waves/block.
__global__ __launch_bounds__(256) void col_stats_kernel(
        const float* __restrict__ x, float* __restrict__ stats) {
    __shared__ float4 shs[4][64];
    __shared__ float4 shs2[4][64];
    int tid = threadIdx.x;
    int c4 = tid & 63;          // float4 chunk of the 256-col row
    int rq = tid >> 6;          // wave id 0..3
    float4 s  = make_float4(0.f, 0.f, 0.f, 0.f);
    float4 s2 = make_float4(0.f, 0.f, 0.f, 0.f);
    for (int r = blockIdx.x * 4 + rq; r < NN; r += STATB * 4) {
        float4 v = *(const float4*)&x[(size_t)r * DD + c4 * 4];
        s.x += v.x; s.y += v.y; s.z += v.z; s.w += v.w;
        s2.x += v.x * v.x; s2.y += v.y * v.y; s2.z += v.z * v.z; s2.w += v.w * v.w;
    }
    shs[rq][c4] = s;
    shs2[rq][c4] = s2;
    __syncthreads();
    if (rq == 0) {
#pragma unroll
        for (int q = 1; q < 4; ++q) {
            float4 a = shs[q][c4], b = shs2[q][c4];
            s.x += a.x; s.y += a.y; s.z += a.z; s.w += a.w;
            s2.x += b.x; s2.y += b.y; s2.z += b.z; s2.w += b.w;
        }
        atomicAdd(&stats[c4 * 4 + 0], s.x);
        atomicAdd(&stats[c4 * 4 + 1], s.y);
        atomicAdd(&stats[c4 * 4 + 2], s.z);
        atomicAdd(&stats[c4 * 4 + 3], s.w);
        atomicAdd(&stats[DD + c4 * 4 + 0], s2.x);
        atomicAdd(&stats[DD + c4 * 4 + 1], s2.y);
        atomicAdd(&stats[DD + c4 * 4 + 2], s2.z);
        atomicAdd(&stats[DD + c4 * 4 + 3], s2.w);
    }
}

// ---------------- fold BN bias: bfold = b_in + sum_j sb[j] * w_in[j][:] ----------------
__global__ void fold_bias_kernel(const float* __restrict__ stats,
                                 const float* __restrict__ gamma,
                                 const float* __restrict__ beta,
                                 const float* __restrict__ w_in,
                                 const float* __restrict__ b_in,
                                 float* __restrict__ bfold) {
    __shared__ float sb[DD];
    int t = threadIdx.x;
    float mean = stats[t] * (1.0f / NN);
    float var  = stats[DD + t] * (1.0f / NN) - mean * mean;
    float a = gamma[t] * rsqrtf(var + 1e-5f);
    sb[t] = beta[t] - mean * a;
    __syncthreads();
    float acc = 0.f;
    for (int j = 0; j < DD; ++j) acc += sb[j] * w_in[j * DD + t];
    bfold[t] = b_in[t] + acc;
}

// ---------------- split W (BN-scaled) into transposed hi/lo fp16: WT[n][k] ----------------
__global__ void split_w1_kernel(const float* __restrict__ stats,
                                const float* __restrict__ gamma,
                                const float* __restrict__ w_in,
                                _Float16* __restrict__ wth, _Float16* __restrict__ wtl) {
    int k = blockIdx.x, n = threadIdx.x;
    float mean = stats[k] * (1.0f / NN);
    float var  = stats[DD + k] * (1.0f / NN) - mean * mean;
    float a = gamma[k] * rsqrtf(var + 1e-5f);
    float v = a * w_in[(size_t)k * DD + n];
    _Float16 hi = (_Float16)v;
    _Float16 lo = (_Float16)(v - (float)hi);
    wth[(size_t)n * DD + k] = hi;
    wtl[(size_t)n * DD + k] = lo;
}

__global__ void split_w_kernel(const float* __restrict__ w, int ncols,
                               _Float16* __restrict__ wth, _Float16* __restrict__ wtl) {
    int k = blockIdx.x, n = threadIdx.x;   // w is [256][ncols]
    float v = w[(size_t)k * ncols + n];
    _Float16 hi = (_Float16)v;
    _Float16 lo = (_Float16)(v - (float)hi);
    wth[(size_t)n * DD + k] = hi;
    wtl[(size_t)n * DD + k] = lo;
}

// ================= CSR build, LDS-aggregated (no device-scope atomics) =================
// A: per-partition-block bucket counts -> Cm[PB][NBK]
__global__ __launch_bounds__(256) void bucket_count_kernel(
        const int* __restrict__ rows, int* __restrict__ Cm) {
    __shared__ int bins[NBK];
    int t = threadIdx.x;
    for (int i = t; i < NBK; i += 256) bins[i] = 0;
    __syncthreads();
    int base = blockIdx.x * CHUNK;
    for (int e = base + t; e < base + CHUNK; e += 256) {
        int r = __builtin_nontemporal_load(&rows[e]);
        atomicAdd(&bins[r >> 7], 1);
    }
    __syncthreads();
    for (int i = t; i < NBK; i += 256) Cm[(size_t)blockIdx.x * NBK + i] = bins[i];
}

// B1: exclusive scan down each bucket column of Cm; totals -> Tb
__global__ __launch_bounds__(256) void scan_col_kernel(int* __restrict__ Cm,
                                                       int* __restrict__ Tb) {
    __shared__ int s[256];
    int b = blockIdx.x;
    int t = threadIdx.x;
    int v0 = Cm[(size_t)(2 * t)     * NBK + b];
    int v1 = Cm[(size_t)(2 * t + 1) * NBK + b];
    int local = v0 + v1;
    s[t] = local;
    __syncthreads();
    for (int off = 1; off < 256; off <<= 1) {
        int xv = 0;
        if (t >= off) xv = s[t - off];
        __syncthreads();
        if (t >= off) s[t] += xv;
        __syncthreads();
    }
    int excl = s[t] - local;
    Cm[(size_t)(2 * t)     * NBK + b] = excl;
    Cm[(size_t)(2 * t + 1) * NBK + b] = excl + v0;
    if (t == 255) Tb[b] = s[255];
}

// B2: exclusive scan of bucket totals -> Bb[0..NBK], Bb[NBK] = EE
__global__ __launch_bounds__(256) void scan_buckets_kernel(const int* __restrict__ Tb,
                                                           int* __restrict__ Bb) {
    __shared__ int s[256];
    int t = threadIdx.x;
    int v[4]; int local = 0;
    for (int i = 0; i < 4; ++i) {
        int idx = t * 4 + i;
        v[i] = (idx < NBK) ? Tb[idx] : 0;
        local += v[i];
    }
    s[t] = local;
    __syncthreads();
    for (int off = 1; off < 256; off <<= 1) {
        int xv = 0;
        if (t >= off) xv = s[t - off];
        __syncthreads();
        if (t >= off) s[t] += xv;
        __syncthreads();
    }
    int excl = s[t] - local;
    int run = excl;
    for (int i = 0; i < 4; ++i) {
        int idx = t * 4 + i;
        if (idx < NBK) Bb[idx] = run;
        run += v[i];
    }
    if (t == 255) Bb[NBK] = EE;
}

// C: scatter edges into bucket-contiguous ebuf, packed (rowlo<<17 | col, val)
__global__ __launch_bounds__(256) void bucket_scatter_kernel(
        const int* __restrict__ rows, const int* __restrict__ cols,
        const float* __restrict__ vals, const int* __restrict__ Cm,
        const int* __restrict__ Bb, int2* __restrict__ ebuf) {
    __shared__ int bins[NBK];
    int t = threadIdx.x;
    for (int i = t; i < NBK; i += 256) bins[i] = 0;
    __syncthreads();
    int base = blockIdx.x * CHUNK;
    for (int e = base + t; e < base + CHUNK; e += 256) {
        int r = __builtin_nontemporal_load(&rows[e]);
        int c = __builtin_nontemporal_load(&cols[e]);
        float v = __builtin_nontemporal_load(&vals[e]);
        int bkt = r >> 7;
        int lr = atomicAdd(&bins[bkt], 1);
        int pos = Bb[bkt] + Cm[(size_t)blockIdx.x * NBK + bkt] + lr;
        ebuf[pos] = make_int2(c | ((r & 127) << 17), __float_as_int(v));
    }
}

// D: per-bucket 128-row hist+scan in LDS -> rp + final row-major CSR edges
__global__ __launch_bounds__(256) void bucket_finalize_kernel(
        const int* __restrict__ Bb, const int2* __restrict__ ebuf,
        int* __restrict__ rp, int2* __restrict__ edges) {
    __shared__ int hist[128];
    __shared__ int excl[128];
    __shared__ int cur[128];
    __shared__ int sc[128];
    int b = blockIdx.x;
    int t = threadIdx.x;
    int e0 = Bb[b], e1 = Bb[b + 1];
    if (t < 128) { hist[t] = 0; cur[t] = 0; }
    __syncthreads();
    for (int e = e0 + t; e < e1; e += 256)
        atomicAdd(&hist[ebuf[e].x >> 17], 1);
    __syncthreads();
    if (t < 128) sc[t] = hist[t];
    __syncthreads();
    for (int off = 1; off < 128; off <<= 1) {
        int xv = 0;
        if (t < 128 && t >= off) xv = sc[t - off];
        __syncthreads();
        if (t < 128 && t >= off) sc[t] += xv;
        __syncthreads();
    }
    if (t < 128) {
        excl[t] = sc[t] - hist[t];
        int gr = b * 128 + t;
        if (gr < NN) rp[gr] = e0 + excl[t];
    }
    if (b == 0 && t == 0) rp[NN] = EE;
    __syncthreads();
    for (int e = e0 + t; e < e1; e += 256) {
        int2 d = ebuf[e];
        int rl = d.x >> 17;
        int lr = atomicAdd(&cur[rl], 1);
        edges[e0 + excl[rl] + lr] = make_int2(d.x & 0x1FFFF, d.y);
    }
}

// ---------------- spmm, feature-half pass (fp16 storage, fp32 accum) ----------------
__global__ __launch_bounds__(256) void spmm_kernel(
        const int* __restrict__ rp, const int2* __restrict__ edges,
        const __half* __restrict__ xin, __half* __restrict__ xout, int ph) {
    int tid = threadIdx.x;
    int lane = tid & 63;
    int sub = lane >> 4;         // edge slot 0..3
    int sl = lane & 15;          // feature chunk (8 halves each)
    int r = __builtin_amdgcn_readfirstlane(blockIdx.x * 4 + (tid >> 6));
    int e0 = rp[r], e1 = rp[r + 1];
    const float4* xi = (const float4*)xin;   // 32 chunks/row; this pass uses [ph*16, ph*16+16)
    const long long* epk = (const long long*)edges;
    int cbase = ph * 16 + sl;

    float acc[8] = {0.f,0.f,0.f,0.f,0.f,0.f,0.f,0.f};

    int base = e0;
    for (; base + 8 <= e1; base += 8) {
        long long p0 = __builtin_nontemporal_load(&epk[base + sub]);
        long long p1 = __builtin_nontemporal_load(&epk[base + 4 + sub]);
        int c0 = (int)(unsigned int)p0, c1 = (int)(unsigned int)p1;
        float v0 = __int_as_float((int)(p0 >> 32));
        float v1 = __int_as_float((int)(p1 >> 32));
        float4 x0 = xi[(size_t)c0 * 32 + cbase];
        float4 x1 = xi[(size_t)c1 * 32 + cbase];
        {
            const __half2* hp = (const __half2*)&x0;
            float2 f0 = __half22float2(hp[0]);
            float2 f1 = __half22float2(hp[1]);
            float2 f2 = __half22float2(hp[2]);
            float2 f3 = __half22float2(hp[3]);
            acc[0] += v0*f0.x; acc[1] += v0*f0.y;
            acc[2] += v0*f1.x; acc[3] += v0*f1.y;
            acc[4] += v0*f2.x; acc[5] += v0*f2.y;
            acc[6] += v0*f3.x; acc[7] += v0*f3.y;
        }
        {
            const __half2* hp = (const __half2*)&x1;
            float2 f0 = __half22float2(hp[0]);
            float2 f1 = __half22float2(hp[1]);
            float2 f2 = __half22float2(hp[2]);
            float2 f3 = __half22float2(hp[3]);
            acc[0] += v1*f0.x; acc[1] += v1*f0.y;
            acc[2] += v1*f1.x; acc[3] += v1*f1.y;
            acc[4] += v1*f2.x; acc[5] += v1*f2.y;
            acc[6] += v1*f3.x; acc[7] += v1*f3.y;
        }
    }
    if (base < e1) {             // tail: 1..7 edges
#pragma unroll
        for (int i = 0; i < 2; ++i) {
            int idx = base + 4*i + sub;
            bool valid = idx < e1;
            int idxc = valid ? idx : e0;
            long long p = epk[idxc];
            int c = (int)(unsigned int)p;
            float v = valid ? __int_as_float((int)(p >> 32)) : 0.f;
            float4 xv = xi[(size_t)c * 32 + cbase];
            const __half2* hp = (const __half2*)&xv;
            float2 f0 = __half22float2(hp[0]);
            float2 f1 = __half22float2(hp[1]);
            float2 f2 = __half22float2(hp[2]);
            float2 f3 = __half22float2(hp[3]);
            acc[0] += v*f0.x; acc[1] += v*f0.y;
            acc[2] += v*f1.x; acc[3] += v*f1.y;
            acc[4] += v*f2.x; acc[5] += v*f2.y;
            acc[6] += v*f3.x; acc[7] += v*f3.y;
        }
    }
    // reduce across the 4 edge slots
#pragma unroll
    for (int j = 0; j < 8; ++j) {
        acc[j] += __shfl_xor(acc[j], 16, 64);
        acc[j] += __shfl_xor(acc[j], 32, 64);
    }
    if (sub == 0) {
        union { __half h[8]; f32x4 f; } u;
#pragma unroll
        for (int j = 0; j < 8; ++j) u.h[j] = __float2half_rn(acc[j]);
        __builtin_nontemporal_store(u.f, (f32x4*)&((float4*)xout)[(size_t)r * 32 + cbase]);
    }
}

// ---------------- MFMA GEMM with split-fp16 precision ----------------
template<bool SPLIT_A, bool TANH, typename Tout, int BN>
__global__ __launch_bounds__(256) void gemm_mfma(
    const void* __restrict__ Av, const _Float16* __restrict__ WTh,
    const _Float16* __restrict__ WTl, const float* __restrict__ bias,
    Tout* __restrict__ C, int M_A, int M_C, int NC)
{
    __shared__ _Float16 As_hi[128 * LSTR];
    __shared__ _Float16 As_lo[(SPLIT_A ? 128 : 1) * LSTR];
    __shared__ _Float16 Ws_hi[BN * LSTR];
    __shared__ _Float16 Ws_lo[BN * LSTR];

    int tid = threadIdx.x;
    int lane = tid & 63;
    int w = tid >> 6;
    int q = lane >> 4;          // quad 0..3
    int r16 = lane & 15;
    int m0 = blockIdx.x * 128;
    int n0 = blockIdx.y * BN;

    constexpr int MT = (BN == 128) ? 4 : 2;
    int wm = (BN == 128) ? (w & 1) * 64 : w * 32;
    int wn = (BN == 128) ? (w >> 1) * 64 : 0;

    f32x4 acc[MT][4];
#pragma unroll
    for (int mt = 0; mt < MT; ++mt)
#pragma unroll
        for (int nt = 0; nt < 4; ++nt) acc[mt][nt] = (f32x4){0.f, 0.f, 0.f, 0.f};

    for (int k0 = 0; k0 < 256; k0 += 32) {
        // ---- stage A tile (128 x 32) ----
        if (SPLIT_A) {
            const float* A = (const float*)Av;
#pragma unroll
            for (int p = 0; p < 4; ++p) {
                int idx = tid + p * 256;          // 1024 float4 chunks
                int m = idx >> 3, kc = idx & 7;
                int gm = m0 + m;
                float4 av = make_float4(0.f, 0.f, 0.f, 0.f);
                if (gm < M_A) av = *(const float4*)&A[(size_t)gm * 256 + k0 + kc * 4];
                half4 hi, lo;
                hi.x = (_Float16)av.x; lo.x = (_Float16)(av.x - (float)hi.x);
                hi.y = (_Float16)av.y; lo.y = (_Float16)(av.y - (float)hi.y);
                hi.z = (_Float16)av.z; lo.z = (_Float16)(av.z - (float)hi.z);
                hi.w = (_Float16)av.w; lo.w = (_Float16)(av.w - (float)hi.w);
                *(half4*)&As_hi[m * LSTR + kc * 4] = hi;
                *(half4*)&As_lo[m * LSTR + kc * 4] = lo;
            }
        } else {
            const _Float16* A = (const _Float16*)Av;
#pragma unroll
            for (int p = 0; p < 2; ++p) {
                int idx = tid + p * 256;          // 512 chunks of 8 halves
                int m = idx >> 2, kc = idx & 3;
                half8 av = *(const half8*)&A[(size_t)(m0 + m) * 256 + k0 + kc * 8];
                *(half8*)&As_hi[m * LSTR + kc * 8] = av;
            }
        }
        // ---- stage W tile (BN x 32, hi+lo) ----
#pragma unroll
        for (int p = 0; p < BN / 64; ++p) {
            int idx = tid + p * 256;
            int n = idx >> 2, kc = idx & 3;
            *(half8*)&Ws_hi[n * LSTR + kc * 8] = *(const half8*)&WTh[(size_t)(n0 + n) * 256 + k0 + kc * 8];
            *(half8*)&Ws_lo[n * LSTR + kc * 8] = *(const half8*)&WTl[(size_t)(n0 + n) * 256 + k0 + kc * 8];
        }
        __syncthreads();

        // ---- fragments ----
        half8 af_h[MT], af_l[MT], wf_h[4], wf_l[4];
#pragma unroll
        for (int mt = 0; mt < MT; ++mt) {
            int mrow = wm + mt * 16 + r16;
            af_h[mt] = *(const half8*)&As_hi[mrow * LSTR + q * 8];
            if (SPLIT_A) af_l[mt] = *(const half8*)&As_lo[mrow * LSTR + q * 8];
        }
#pragma unroll
        for (int nt = 0; nt < 4; ++nt) {
            int nrow = wn + nt * 16 + r16;
            wf_h[nt] = *(const half8*)&Ws_hi[nrow * LSTR + q * 8];
            wf_l[nt] = *(const half8*)&Ws_lo[nrow * LSTR + q * 8];
        }
        // ---- MFMA ----
#pragma unroll
        for (int mt = 0; mt < MT; ++mt)
#pragma unroll
            for (int nt = 0; nt < 4; ++nt) {
                acc[mt][nt] = mfma16(af_h[mt], wf_h[nt], acc[mt][nt]);
                if (SPLIT_A) acc[mt][nt] = mfma16(af_l[mt], wf_h[nt], acc[mt][nt]);
                acc[mt][nt] = mfma16(af_h[mt], wf_l[nt], acc[mt][nt]);
            }
        __syncthreads();
    }

    // ---- epilogue: bias (+ tanh) -> store (C layout: col=lane&15, row=quad*4+reg) ----
#pragma unroll
    for (int nt = 0; nt < 4; ++nt) {
        float b = bias[n0 + wn + nt * 16 + r16];
        int gc = n0 + wn + nt * 16 + r16;
#pragma unroll
        for (int mt = 0; mt < MT; ++mt) {
#pragma unroll
            for (int r = 0; r < 4; ++r) {
                int gm = m0 + wm + mt * 16 + q * 4 + r;
                float v = acc[mt][nt][r] + b;
                if (TANH) v = tanhf(v);
                if (gm < M_C) C[(size_t)gm * NC + gc] = (Tout)v;
            }
        }
    }
}

extern "C" void kernel_launch(void* const* d_in, const int* in_sizes, int n_in,
                              void* d_out, int out_size, void* d_ws, size_t ws_size,
                              hipStream_t stream) {
    const float* x      = (const float*)d_in[0];
    const int*   erows  = (const int*)d_in[1];
    const int*   ecols  = (const int*)d_in[2];
    const float* evals  = (const float*)d_in[3];
    const float* gamma  = (const float*)d_in[4];
    const float* beta   = (const float*)d_in[5];
    const float* w_in   = (const float*)d_in[6];
    const float* b_in   = (const float*)d_in[7];
    const float* w_conv = (const float*)d_in[8];
    const float* b_conv = (const float*)d_in[9];
    const float* w_out  = (const float*)d_in[10];
    const float* b_out  = (const float*)d_in[11];
    float* out = (float*)d_out;

    char* ws = (char*)d_ws;
    size_t off = 0;
    auto alloc = [&](size_t bytes) -> void* {
        void* p = ws + off;
        off = (off + bytes + 255) & ~(size_t)255;
        return p;
    };
    _Float16* h1   = (_Float16*)alloc((size_t)NNP * DD * 2);
    _Float16* h2   = (_Float16*)alloc((size_t)NNP * DD * 2);
    int2*  edges = (int2*) alloc((size_t)EE * 8);
    int2*  ebuf  = (int2*) alloc((size_t)EE * 8);
    int*   Cm    = (int*)  alloc((size_t)PB * NBK * 4);
    int*   Tb    = (int*)  alloc((size_t)NBK * 4);
    int*   Bb    = (int*)  alloc((size_t)(NBK + 1) * 4);
    int*   rp    = (int*)  alloc((size_t)(NN + 1) * 4);
    float* stats = (float*)alloc(2 * DD * 4);
    _Float16* wt1h = (_Float16*)alloc((size_t)DD * DD * 2);
    _Float16* wt1l = (_Float16*)alloc((size_t)DD * DD * 2);
    _Float16* wt2h = (_Float16*)alloc((size_t)DD * DD * 2);
    _Float16* wt2l = (_Float16*)alloc((size_t)DD * DD * 2);
    _Float16* wt3h = (_Float16*)alloc((size_t)DOUTC * DD * 2);
    _Float16* wt3l = (_Float16*)alloc((size_t)DOUTC * DD * 2);
    float* bfold = (float*)alloc(DD * 4);

    hipMemsetAsync(stats, 0, 2 * DD * 4, stream);

    // CSR build: LDS-bucketed, no device-scope atomics
    bucket_count_kernel<<<PB, 256, 0, stream>>>(erows, Cm);
    scan_col_kernel<<<NBK, 256, 0, stream>>>(Cm, Tb);
    scan_buckets_kernel<<<1, 256, 0, stream>>>(Tb, Bb);
    bucket_scatter_kernel<<<PB, 256, 0, stream>>>(erows, ecols, evals, Cm, Bb, ebuf);
    bucket_finalize_kernel<<<NBK, 256, 0, stream>>>(Bb, ebuf, rp, edges);

    // BN stats + weight prep
    col_stats_kernel<<<STATB, 256, 0, stream>>>(x, stats);
    fold_bias_kernel<<<1, 256, 0, stream>>>(stats, gamma, beta, w_in, b_in, bfold);
    split_w1_kernel<<<DD, DD, 0, stream>>>(stats, gamma, w_in, wt1h, wt1l);
    split_w_kernel<<<DD, DD, 0, stream>>>(w_conv, DD, wt2h, wt2l);
    split_w_kernel<<<DD, DOUTC, 0, stream>>>(w_out, DOUTC, wt3h, wt3l);

    dim3 g2(NNP / 128, 2), g1(NNP / 128, 1);
    // GEMM1: fp32 A (split) -> tanh -> fp16 h1
    gemm_mfma<true, true, _Float16, 128><<<g2, 256, 0, stream>>>(
        x, wt1h, wt1l, bfold, h1, NN, NNP, DD);

    // 4 spmm hops, 2 feature-half passes each
    spmm_kernel<<<NN / 4, 256, 0, stream>>>(rp, edges, (const __half*)h1, (__half*)h2, 0);
    spmm_kernel<<<NN / 4, 256, 0, stream>>>(rp, edges, (const __half*)h1, (__half*)h2, 1);
    spmm_kernel<<<NN / 4, 256, 0, stream>>>(rp, edges, (const __half*)h2, (__half*)h1, 0);
    spmm_kernel<<<NN / 4, 256, 0, stream>>>(rp, edges, (const __half*)h2, (__half*)h1, 1);
    spmm_kernel<<<NN / 4, 256, 0, stream>>>(rp, edges, (const __half*)h1, (__half*)h2, 0);
    spmm_kernel<<<NN / 4, 256, 0, stream>>>(rp, edges, (const __half*)h1, (__half*)h2, 1);
    spmm_kernel<<<NN / 4, 256, 0, stream>>>(rp, edges, (const __half*)h2, (__half*)h1, 0);
    spmm_kernel<<<NN / 4, 256, 0, stream>>>(rp, edges, (const __half*)h2, (__half*)h1, 1);

    // GEMM2: fp16 A -> tanh -> fp16 h2
    gemm_mfma<false, true, _Float16, 128><<<g2, 256, 0, stream>>>(
        h1, wt2h, wt2l, b_conv, h2, NNP, NNP, DD);
    // GEMM3: fp16 A -> fp32 logits
    gemm_mfma<false, false, float, 64><<<g1, 256, 0, stream>>>(
        h2, wt3h, wt3l, b_out, out, NNP, NN, DOUTC);
}